// Round 11
// baseline (741.501 us; speedup 1.0000x reference)
//
#include <hip/hip_runtime.h>
#include <hip/hip_fp16.h>

// GraphSAGE_GAT: SAGE(mean)x2 -> GAT(2 heads, softmax) -> edge MLP
// N=100000, E=1600000, D=32, H=2, EF=16.
// R11: two-phase bucketed CSR fill. R10 showed fill_k writes 110MB HBM for a
//      6.4MB payload (scattered 4B stores; NT made it line-granular). Phase A
//      appends (soff,dst) into 8 XCD-correlated slices per 512-dst bucket
//      (sequential, L2-mergeable). Phase B scatters within a contiguous 32KB
//      soff window per bucket via LDS counters (single XCD, full lines).
//      All R10 NT hints and 8-deep unrolls reverted to proven R9 kernels.

#define DD 32
#define HH 2
#define EFF 16

#define BKT_SHIFT 9
#define BKT_SIZE 512
#define SEG_CAP 1536

__device__ __forceinline__ float lrelu(float x) { return x > 0.f ? x : 0.2f * x; }

// ---- CSR build: histogram of dst ----
__global__ void hist_k(const int* __restrict__ dst, int* __restrict__ deg, int E) {
    int e = blockIdx.x * blockDim.x + threadIdx.x;
    if (e < E) atomicAdd(&deg[dst[e]], 1);
}

// ---- scan phase 1: per-1024-chunk exclusive scan + chunk totals ----
__global__ void scan1_k(const int* __restrict__ deg, int* __restrict__ rowptr,
                        int* __restrict__ blockSums, int N) {
    __shared__ int s_s[256];
    int blk = blockIdx.x, t = threadIdx.x;
    int base = blk * 1024 + t * 4;
    int v[4];
    int s = 0;
#pragma unroll
    for (int i = 0; i < 4; i++) {
        v[i] = (base + i < N) ? deg[base + i] : 0;
        s += v[i];
    }
    s_s[t] = s;
    __syncthreads();
    for (int off = 1; off < 256; off <<= 1) {
        int x = (t >= off) ? s_s[t - off] : 0;
        __syncthreads();
        s_s[t] += x;
        __syncthreads();
    }
    int excl = s_s[t] - s;
#pragma unroll
    for (int i = 0; i < 4; i++) {
        if (base + i < N) rowptr[base + i] = excl;
        excl += v[i];
    }
    if (t == 255) blockSums[blk] = s_s[255];
}

// ---- scan phase 2: scan the chunk totals (<=128 chunks) ----
__global__ void scan2_k(int* __restrict__ blockSums, int* __restrict__ rowptrN, int NB) {
    __shared__ int s_s[128];
    int t = threadIdx.x;
    int v = (t < NB) ? blockSums[t] : 0;
    s_s[t] = v;
    __syncthreads();
    for (int off = 1; off < 128; off <<= 1) {
        int x = (t >= off) ? s_s[t - off] : 0;
        __syncthreads();
        s_s[t] += x;
        __syncthreads();
    }
    if (t < NB) blockSums[t] = s_s[t] - v;  // exclusive
    if (t == 127) *rowptrN = s_s[127];      // total = E
}

// ---- scan phase 3: add chunk offsets ----
__global__ void scan3_k(int* __restrict__ rowptr, const int* __restrict__ blockSums, int N) {
    int i = blockIdx.x * blockDim.x + threadIdx.x;
    if (i < N) rowptr[i] += blockSums[i >> 10];
}

// ---- fill phase A: append (src*64, dst) into per-(bucket,slice) segments ----
// slice = blockIdx&7 correlates with XCD -> appends to a segment are
// single-XCD and sequential -> L2 merges the 8B stores into full lines.
__global__ void bucket_fill_k(const int* __restrict__ src, const int* __restrict__ dst,
                              int* __restrict__ segCnt, int2* __restrict__ segBuf,
                              int2* __restrict__ ovf, int* __restrict__ ovfCnt, int E) {
    int e = blockIdx.x * blockDim.x + threadIdx.x;
    if (e >= E) return;
    int d = dst[e];
    int sv = src[e] * 64;
    int seg = ((d >> BKT_SHIFT) << 3) | (blockIdx.x & 7);
    int p = atomicAdd(&segCnt[seg], 1);
    if (p < SEG_CAP) {
        segBuf[(size_t)seg * SEG_CAP + p] = make_int2(sv, d);
    } else {
        int q = atomicAdd(ovfCnt, 1);
        ovf[q] = make_int2(sv, d);  // ovf has capacity E: never drops
    }
}

// ---- fill phase B: one block per bucket; LDS counters seeded from rowptr;
// scatter confined to the bucket's contiguous soff window ----
__global__ void bucket_scatter_k(const int* __restrict__ rowptr,
                                 const int* __restrict__ segCnt,
                                 const int2* __restrict__ segBuf,
                                 const int2* __restrict__ ovf,
                                 const int* __restrict__ ovfCnt,
                                 int* __restrict__ soff, int N) {
    __shared__ int cnt[BKT_SIZE];
    int b = blockIdx.x;
    int base = b << BKT_SHIFT;
    int t = threadIdx.x;
    for (int i = t; i < BKT_SIZE; i += blockDim.x) {
        int d = base + i;
        cnt[i] = (d < N) ? rowptr[d] : 0;
    }
    __syncthreads();
#pragma unroll 1
    for (int s = 0; s < 8; s++) {
        int seg = (b << 3) | s;
        int c = min(segCnt[seg], SEG_CAP);
        const int2* sb = segBuf + (size_t)seg * SEG_CAP;
        for (int i = t; i < c; i += blockDim.x) {
            int2 en = sb[i];
            int pos = atomicAdd(&cnt[en.y - base], 1);
            soff[pos] = en.x;
        }
    }
    int O = *ovfCnt;
    for (int i = t; i < O; i += blockDim.x) {
        int2 en = ovf[i];
        if ((en.y >> BKT_SHIFT) == b) {
            int pos = atomicAdd(&cnt[en.y - base], 1);
            soff[pos] = en.x;
        }
    }
}

// ---- convert fp32 -> fp16 ----
__global__ void cvt_k(const float* __restrict__ in, __half* __restrict__ out, int n) {
    int i = blockIdx.x * blockDim.x + threadIdx.x;
    if (i < n) out[i] = __float2half(in[i]);
}

// ---- SAGE fused: gather-mean + lin_l + lin_r + relu -> fp16 (bounded) ----
// one 32-lane group per node
__global__ void sage_fused16(const __half* __restrict__ x, const int* __restrict__ rowptr,
                             const int* __restrict__ soff, const float* __restrict__ wl,
                             const float* __restrict__ bl, const float* __restrict__ wr,
                             __half* __restrict__ out, int N) {
    __shared__ float s_wl[DD * DD];
    __shared__ float s_wr[DD * DD];
    __shared__ float s_b[DD];
    for (int i = threadIdx.x; i < DD * DD; i += blockDim.x) {
        s_wl[i] = wl[i];
        s_wr[i] = wr[i];
    }
    if (threadIdx.x < DD) s_b[threadIdx.x] = bl[threadIdx.x];
    __syncthreads();
    int gid = blockIdx.x * blockDim.x + threadIdx.x;
    int n = gid >> 5;
    if (n >= N) return;
    int k = gid & 31;
    int lo = rowptr[n], hi = rowptr[n + 1];
    const char* xb = (const char*)x;
    float a0 = 0.f, a1 = 0.f, a2 = 0.f, a3 = 0.f;
    int j = lo;
    for (; j + 3 < hi; j += 4) {
        int o0 = soff[j], o1 = soff[j + 1], o2 = soff[j + 2], o3 = soff[j + 3];
        a0 += __half2float(*(const __half*)(xb + o0 + k * 2));
        a1 += __half2float(*(const __half*)(xb + o1 + k * 2));
        a2 += __half2float(*(const __half*)(xb + o2 + k * 2));
        a3 += __half2float(*(const __half*)(xb + o3 + k * 2));
    }
    for (; j < hi; j++) a0 += __half2float(*(const __half*)(xb + soff[j] + k * 2));
    float mean = ((a0 + a1) + (a2 + a3)) / fmaxf((float)(hi - lo), 1.0f);
    float xv = __half2float(x[n * DD + k]);
    float o = s_b[k];
#pragma unroll
    for (int i = 0; i < DD; i++) {
        o += __shfl(mean, i, 32) * s_wl[i * DD + k];
        o += __shfl(xv, i, 32) * s_wr[i * DD + k];
    }
    out[n * DD + k] = __float2half(fmaxf(o, 0.f));
}

// ---- c_s/c_d precompute: c4[i] = (W att_src)[i,h], (W att_dst)[i,h] ----
__global__ void prep_c_k(const float* __restrict__ w, const float* __restrict__ att_src,
                         const float* __restrict__ att_dst, float4* __restrict__ c4) {
    int i = threadIdx.x;
    if (i >= DD) return;
    float cs0 = 0.f, cs1 = 0.f, cd0 = 0.f, cd1 = 0.f;
    for (int d = 0; d < DD; d++) {
        float w0 = w[i * (HH * DD) + d], w1 = w[i * (HH * DD) + DD + d];
        cs0 += w0 * att_src[d];
        cs1 += w1 * att_src[DD + d];
        cd0 += w0 * att_dst[d];
        cd1 += w1 * att_dst[DD + d];
    }
    c4[i] = make_float4(cs0, cs1, cd0, cd1);
}

// ---- GAT scores: thread-per-node dot products against c_s/c_d (bounded) ----
__global__ void gat_scores_v2(const __half* __restrict__ x2, const float4* __restrict__ c4,
                              float2* __restrict__ a_s, float2* __restrict__ a_d, int N) {
    __shared__ float4 s_c[DD];
    if (threadIdx.x < DD) s_c[threadIdx.x] = c4[threadIdx.x];
    __syncthreads();
    int n = blockIdx.x * blockDim.x + threadIdx.x;
    if (n >= N) return;
    const __half2* xr = (const __half2*)(x2 + (size_t)n * DD);
    float as0 = 0.f, as1 = 0.f, ad0 = 0.f, ad1 = 0.f;
#pragma unroll
    for (int i2 = 0; i2 < 16; i2++) {
        float2 f = __half22float2(xr[i2]);
        float4 ca = s_c[i2 * 2], cb = s_c[i2 * 2 + 1];
        as0 += f.x * ca.x + f.y * cb.x;
        as1 += f.x * ca.y + f.y * cb.y;
        ad0 += f.x * ca.z + f.y * cb.z;
        ad1 += f.x * ca.w + f.y * cb.w;
    }
    a_s[n] = make_float2(as0, as1);
    a_d[n] = make_float2(ad0, ad1);
}

// ---- per-edge softmax weights, node-parallel (d = n implicit) ----
__global__ void edge_w_v2(const int* __restrict__ rowptr, const int* __restrict__ soff,
                          const float2* __restrict__ a_s, const float2* __restrict__ a_d,
                          __half2* __restrict__ ews, int N) {
    int gid = blockIdx.x * blockDim.x + threadIdx.x;
    int n = gid >> 5;
    if (n >= N) return;
    int kk = gid & 31;
    int lo = rowptr[n], hi = rowptr[n + 1];
    float2 ad = a_d[n];
    const char* asb = (const char*)a_s;
    for (int j = lo + kk; j < hi; j += 32) {
        float2 as = *(const float2*)(asb + (soff[j] >> 3));  // s*8
        float w0 = __expf(lrelu(as.x + ad.x));
        float w1 = __expf(lrelu(as.y + ad.y));
        ews[j] = __floats2half2_rn(w0, w1);
    }
}

// ---- GAT aggregate v6: 32 lanes/node (2 nodes/wave), bounded grid;
//      one gather serves both heads -> W transform -> head-mean+bias+relu
//      -> fused mlp-pre ----
__global__ void gat_agg_v6(const __half* __restrict__ x2, const float2* __restrict__ a_s,
                           const float2* __restrict__ a_d, const int* __restrict__ rowptr,
                           const int* __restrict__ soff, const __half2* __restrict__ ews,
                           const float* __restrict__ gw, const float* __restrict__ bias,
                           const float* __restrict__ w1, const float* __restrict__ b1,
                           __half* __restrict__ Ps, __half* __restrict__ Pd, int N) {
    __shared__ float s_gw[DD * HH * DD];  // gat W: 32 x 64
    __shared__ float s_w1[2 * DD * DD];   // mlp w1 rows 0..63
    __shared__ float s_b1[DD];
    __shared__ float s_bias[DD];
    int t = threadIdx.x;
    for (int i = t; i < DD * HH * DD; i += blockDim.x) s_gw[i] = gw[i];
    for (int i = t; i < 2 * DD * DD; i += blockDim.x) s_w1[i] = w1[i];
    if (t < DD) {
        s_b1[t] = b1[t];
        s_bias[t] = bias[t];
    }
    __syncthreads();
    int gid = blockIdx.x * blockDim.x + t;
    int n = gid >> 5;
    if (n >= N) return;
    int kk = gid & 31;
    const char* xb = (const char*)x2;
    int lo = rowptr[n], hi = rowptr[n + 1];
    float2 as = a_s[n], ad = a_d[n];
    float ws0 = __expf(lrelu(as.x + ad.x));
    float ws1 = __expf(lrelu(as.y + ad.y));
    float xvs = __half2float(x2[n * DD + kk]);
    float den0 = ws0, den1 = ws1;
    float y0a = ws0 * xvs, y1a = ws1 * xvs;
    float y0b = 0.f, y1b = 0.f;
    int j = lo;
    for (; j + 3 < hi; j += 4) {
        int o0 = soff[j], o1 = soff[j + 1], o2 = soff[j + 2], o3 = soff[j + 3];
        float2 e0 = __half22float2(ews[j]);
        float2 e1 = __half22float2(ews[j + 1]);
        float2 e2 = __half22float2(ews[j + 2]);
        float2 e3 = __half22float2(ews[j + 3]);
        float xv0 = __half2float(*(const __half*)(xb + o0 + kk * 2));
        float xv1 = __half2float(*(const __half*)(xb + o1 + kk * 2));
        float xv2 = __half2float(*(const __half*)(xb + o2 + kk * 2));
        float xv3 = __half2float(*(const __half*)(xb + o3 + kk * 2));
        den0 += (e0.x + e1.x) + (e2.x + e3.x);
        den1 += (e0.y + e1.y) + (e2.y + e3.y);
        y0a += e0.x * xv0 + e2.x * xv2;
        y1a += e0.y * xv0 + e2.y * xv2;
        y0b += e1.x * xv1 + e3.x * xv3;
        y1b += e1.y * xv1 + e3.y * xv3;
    }
    for (; j < hi; j++) {
        int o0 = soff[j];
        float2 e0 = __half22float2(ews[j]);
        float xv0 = __half2float(*(const __half*)(xb + o0 + kk * 2));
        den0 += e0.x;
        den1 += e0.y;
        y0a += e0.x * xv0;
        y1a += e0.y * xv0;
    }
    float u0 = (y0a + y0b) / (den0 + 1e-16f);
    float u1 = (y1a + y1b) / (den1 + 1e-16f);
    // out[kk] = 0.5*(u0 @ Wg[:,kk] + u1 @ Wg[:,32+kk]) + bias, relu
    float o = 0.f;
#pragma unroll
    for (int i = 0; i < DD; i++) {
        float c0 = __shfl(u0, i, 32), c1 = __shfl(u1, i, 32);
        o += c0 * s_gw[i * (HH * DD) + kk] + c1 * s_gw[i * (HH * DD) + DD + kk];
    }
    o = fmaxf(0.5f * o + s_bias[kk], 0.f);
    // fused mlp-pre: Ps (rows 0..31 of w1, +b1), Pd (rows 32..63)
    float ps = s_b1[kk], pd = 0.f;
#pragma unroll
    for (int i = 0; i < DD; i++) {
        float oi = __shfl(o, i, 32);
        ps += oi * s_w1[i * DD + kk];
        pd += oi * s_w1[(DD + i) * DD + kk];
    }
    Ps[n * DD + kk] = __float2half(ps);
    Pd[n * DD + kk] = __float2half(pd);
}

// ---- Edge MLP: acc = Ps[s] + Pd[d] + W1e*ea; out = relu(acc) . w2 + b2 ----
// one thread per edge, straight-line body
__device__ __forceinline__ void add_half_row(const __half* __restrict__ row, float acc[DD]) {
    const uint4* r4 = (const uint4*)row;
#pragma unroll
    for (int c = 0; c < 4; c++) {
        uint4 u = r4[c];
        unsigned uu[4] = {u.x, u.y, u.z, u.w};
#pragma unroll
        for (int t = 0; t < 4; t++) {
            __half2 h2 = *reinterpret_cast<const __half2*>(&uu[t]);
            float2 f = __half22float2(h2);
            acc[c * 8 + t * 2 + 0] += f.x;
            acc[c * 8 + t * 2 + 1] += f.y;
        }
    }
}

__global__ void edge_mlp_v3(const __half* __restrict__ Ps, const __half* __restrict__ Pd,
                            const float* __restrict__ eattr, const int* __restrict__ src,
                            const int* __restrict__ dst, const float* __restrict__ w1e,
                            const float* __restrict__ w2, const float* __restrict__ b2,
                            float* __restrict__ out, int E) {
    __shared__ float s_we[EFF * DD];  // rows 64..79 of w1
    __shared__ float s_w2[DD];
    for (int i = threadIdx.x; i < EFF * DD; i += blockDim.x) s_we[i] = w1e[i];
    if (threadIdx.x < DD) s_w2[threadIdx.x] = w2[threadIdx.x];
    __syncthreads();
    int e = blockIdx.x * blockDim.x + threadIdx.x;
    if (e >= E) return;
    float b2v = b2[0];
    int s = src[e], d = dst[e];
    float acc[DD] = {};
    add_half_row(Ps + (size_t)s * DD, acc);
    add_half_row(Pd + (size_t)d * DD, acc);
    const float4* ea4 = (const float4*)(eattr + (size_t)e * EFF);
#pragma unroll
    for (int c = 0; c < 4; c++) {
        float4 v = ea4[c];
        const float va[4] = {v.x, v.y, v.z, v.w};
#pragma unroll
        for (int r = 0; r < 4; r++) {
#pragma unroll
            for (int j4 = 0; j4 < 8; j4++) {
                const float4 w = *(const float4*)(s_we + (c * 4 + r) * DD + j4 * 4);
                acc[j4 * 4 + 0] += va[r] * w.x;
                acc[j4 * 4 + 1] += va[r] * w.y;
                acc[j4 * 4 + 2] += va[r] * w.z;
                acc[j4 * 4 + 3] += va[r] * w.w;
            }
        }
    }
    float p = b2v;
#pragma unroll
    for (int j = 0; j < DD; j++) p += fmaxf(acc[j], 0.f) * s_w2[j];
    out[e] = p;
}

extern "C" void kernel_launch(void* const* d_in, const int* in_sizes, int n_in,
                              void* d_out, int out_size, void* d_ws, size_t ws_size,
                              hipStream_t stream) {
    const int E = in_sizes[0] / 2;
    const int N = in_sizes[2] / DD;

    const int* src = (const int*)d_in[0];
    const int* dst = src + E;
    const float* edge_attr = (const float*)d_in[1];
    const float* node_emb = (const float*)d_in[2];
    const float* sage1_wl = (const float*)d_in[3];
    const float* sage1_bl = (const float*)d_in[4];
    const float* sage1_wr = (const float*)d_in[5];
    const float* sage2_wl = (const float*)d_in[6];
    const float* sage2_bl = (const float*)d_in[7];
    const float* sage2_wr = (const float*)d_in[8];
    const float* gat_w = (const float*)d_in[9];
    const float* gat_att_src = (const float*)d_in[10];
    const float* gat_att_dst = (const float*)d_in[11];
    const float* gat_bias = (const float*)d_in[12];
    const float* mlp_w1 = (const float*)d_in[13];
    const float* mlp_b1 = (const float*)d_in[14];
    const float* mlp_w2 = (const float*)d_in[15];
    const float* mlp_b2 = (const float*)d_in[16];
    float* out = (float*)d_out;

    const int nBuckets = (N + BKT_SIZE - 1) >> BKT_SHIFT;

    // Workspace layout (256B-aligned chunks)
    char* ws = (char*)d_ws;
    size_t off = 0;
    auto alloc = [&](size_t bytes) {
        char* p = ws + off;
        off = (off + bytes + 255) & ~(size_t)255;
        return p;
    };
    int* deg = (int*)alloc((size_t)N * 4);
    int* rowptr = (int*)alloc((size_t)(N + 1) * 4);
    int* blockSums = (int*)alloc(128 * 4);
    int* soff = (int*)alloc((size_t)E * 4);
    __half2* ews = (__half2*)alloc((size_t)E * 4);
    __half* x0h = (__half*)alloc((size_t)N * DD * 2);
    __half* x1h = (__half*)alloc((size_t)N * DD * 2);
    __half* x2h = (__half*)alloc((size_t)N * DD * 2);
    float2* a_s = (float2*)alloc((size_t)N * 8);
    float2* a_d = (float2*)alloc((size_t)N * 8);
    float4* c4 = (float4*)alloc(DD * 16);
    __half* Ps = (__half*)alloc((size_t)N * DD * 2);
    __half* Pd = (__half*)alloc((size_t)N * DD * 2);
    int* segCnt = (int*)alloc((size_t)nBuckets * 8 * 4);
    int* ovfCnt = (int*)alloc(4);
    int2* segBuf = (int2*)alloc((size_t)nBuckets * 8 * SEG_CAP * 8);
    int2* ovf = (int2*)alloc((size_t)E * 8);

    const int BS = 256;
    const int gE = (E + BS - 1) / BS;
    const int gN32 = (N * 32 + BS - 1) / BS;
    const int gN1 = (N + BS - 1) / BS;
    const int NB = (N + 1023) / 1024;

    // ---- CSR build ----
    hipMemsetAsync(deg, 0, (size_t)N * sizeof(int), stream);
    hipMemsetAsync(segCnt, 0, (size_t)nBuckets * 8 * sizeof(int), stream);
    hipMemsetAsync(ovfCnt, 0, sizeof(int), stream);
    hist_k<<<gE, BS, 0, stream>>>(dst, deg, E);
    scan1_k<<<NB, 256, 0, stream>>>(deg, rowptr, blockSums, N);
    scan2_k<<<1, 128, 0, stream>>>(blockSums, rowptr + N, NB);
    scan3_k<<<gN1, BS, 0, stream>>>(rowptr, blockSums, N);
    bucket_fill_k<<<gE, BS, 0, stream>>>(src, dst, segCnt, segBuf, ovf, ovfCnt, E);
    bucket_scatter_k<<<nBuckets, BS, 0, stream>>>(rowptr, segCnt, segBuf, ovf, ovfCnt,
                                                  soff, N);

    // ---- fp16 input conversion ----
    cvt_k<<<gN32, BS, 0, stream>>>(node_emb, x0h, N * DD);

    // ---- SAGE layers ----
    sage_fused16<<<gN32, BS, 0, stream>>>(x0h, rowptr, soff, sage1_wl, sage1_bl, sage1_wr,
                                          x1h, N);
    sage_fused16<<<gN32, BS, 0, stream>>>(x1h, rowptr, soff, sage2_wl, sage2_bl, sage2_wr,
                                          x2h, N);

    // ---- GAT (+ fused mlp-pre) ----
    prep_c_k<<<1, 64, 0, stream>>>(gat_w, gat_att_src, gat_att_dst, c4);
    gat_scores_v2<<<gN1, BS, 0, stream>>>(x2h, c4, a_s, a_d, N);
    edge_w_v2<<<gN32, BS, 0, stream>>>(rowptr, soff, a_s, a_d, ews, N);
    gat_agg_v6<<<gN32, BS, 0, stream>>>(x2h, a_s, a_d, rowptr, soff, ews, gat_w, gat_bias,
                                        mlp_w1, mlp_b1, Ps, Pd, N);

    // ---- Edge MLP ----
    edge_mlp_v3<<<gE, BS, 0, stream>>>(Ps, Pd, edge_attr, src, dst,
                                       mlp_w1 + 2 * DD * DD, mlp_w2, mlp_b2, out, E);
}

// Round 12
// 481.528 us; speedup vs baseline: 1.5399x; 1.5399x over previous
//
#include <hip/hip_runtime.h>
#include <hip/hip_fp16.h>

// GraphSAGE_GAT: SAGE(mean)x2 -> GAT(2 heads, softmax) -> edge MLP
// N=100000, E=1600000, D=32, H=2, EF=16.
// R12: CSR fill via 3-phase counting sort (per-block LDS histograms +
//      pre-scanned private windows -> ZERO global atomics; R11's segment
//      counters died on hot-counter serialization, R9's direct scatter on
//      17x write amplification). edge_w fused into gat_agg (a_s is an
//      800KB L2-resident table; exp is chain-free). gat_scores fused into
//      sage2 epilogue. Everything else = proven R9 kernels.

#define DD 32
#define HH 2
#define EFF 16

#define EB 4096      // edges per radix block
#define PB_T 512     // threads in radix A/B
#define BIN_SHIFT 8  // dst>>8 -> coarse bin (256 nodes/bin)

__device__ __forceinline__ float lrelu(float x) { return x > 0.f ? x : 0.2f * x; }

// ---- histogram of dst (node degrees) ----
__global__ void hist_k(const int* __restrict__ dst, int* __restrict__ deg, int E) {
    int e = blockIdx.x * blockDim.x + threadIdx.x;
    if (e < E) atomicAdd(&deg[dst[e]], 1);
}

// ---- generic scan phase 1: per-1024-chunk exclusive scan + chunk totals ----
__global__ void scan1_k(const int* __restrict__ in, int* __restrict__ out,
                        int* __restrict__ blockSums, int M) {
    __shared__ int s_s[256];
    int blk = blockIdx.x, t = threadIdx.x;
    int base = blk * 1024 + t * 4;
    int v[4];
    int s = 0;
#pragma unroll
    for (int i = 0; i < 4; i++) {
        v[i] = (base + i < M) ? in[base + i] : 0;
        s += v[i];
    }
    s_s[t] = s;
    __syncthreads();
    for (int off = 1; off < 256; off <<= 1) {
        int x = (t >= off) ? s_s[t - off] : 0;
        __syncthreads();
        s_s[t] += x;
        __syncthreads();
    }
    int excl = s_s[t] - s;
#pragma unroll
    for (int i = 0; i < 4; i++) {
        if (base + i < M) out[base + i] = excl;
        excl += v[i];
    }
    if (t == 255) blockSums[blk] = s_s[255];
}

// ---- generic scan phase 2: scan the chunk totals (<=256 chunks) ----
__global__ void scan2_k(int* __restrict__ blockSums, int* __restrict__ totalOut, int NB) {
    __shared__ int s_s[256];
    int t = threadIdx.x;
    int v = (t < NB) ? blockSums[t] : 0;
    s_s[t] = v;
    __syncthreads();
    for (int off = 1; off < 256; off <<= 1) {
        int x = (t >= off) ? s_s[t - off] : 0;
        __syncthreads();
        s_s[t] += x;
        __syncthreads();
    }
    if (t < NB) blockSums[t] = s_s[t] - v;  // exclusive
    if (t == 255) *totalOut = s_s[255];
}

// ---- generic scan phase 3: add chunk offsets ----
__global__ void scan3_k(int* __restrict__ out, const int* __restrict__ blockSums, int M) {
    int i = blockIdx.x * blockDim.x + threadIdx.x;
    if (i < M) out[i] += blockSums[i >> 10];
}

// ---- radix A: per-block coarse histogram (bin = dst>>8), LDS only ----
__global__ void radixA_k(const int* __restrict__ dst, int* __restrict__ histA, int E,
                         int NBLK, int NBINS) {
    __shared__ int s_h[512];
    int blk = blockIdx.x, t = threadIdx.x;
    for (int b = t; b < 512; b += PB_T) s_h[b] = 0;
    __syncthreads();
    int e0 = blk * EB;
    for (int i = t; i < EB; i += PB_T) {
        int e = e0 + i;
        if (e < E) atomicAdd(&s_h[dst[e] >> BIN_SHIFT], 1);
    }
    __syncthreads();
    for (int b = t; b < NBINS; b += PB_T) histA[b * NBLK + blk] = s_h[b];
}

// ---- radix B: place (src*64,dst) into this block's private window per bin ----
// base offsets pre-scanned -> zero global atomics; writes are short sequential
// runs per bin window -> L2-merged.
__global__ void radixB_k(const int* __restrict__ src, const int* __restrict__ dst,
                         const int* __restrict__ histScan, int2* __restrict__ pairs,
                         int E, int NBLK, int NBINS) {
    __shared__ int s_base[512];
    int blk = blockIdx.x, t = threadIdx.x;
    for (int b = t; b < NBINS; b += PB_T) s_base[b] = histScan[b * NBLK + blk];
    __syncthreads();
    int e0 = blk * EB;
    for (int i = t; i < EB; i += PB_T) {
        int e = e0 + i;
        if (e < E) {
            int d = dst[e];
            int pos = atomicAdd(&s_base[d >> BIN_SHIFT], 1);  // LDS atomic only
            pairs[pos] = make_int2(src[e] * 64, d);
        }
    }
}

// ---- radix C: one block per bin; LDS counters seeded from rowptr; scatter
// confined to the bin's contiguous ~16KB soff window ----
__global__ void radixC_k(const int* __restrict__ rowptr, const int* __restrict__ histScan,
                         const int2* __restrict__ pairs, int* __restrict__ soff, int N,
                         int NBLK, int NBINS, int E) {
    __shared__ int cnt[256];
    int b = blockIdx.x, t = threadIdx.x;
    int base = b << BIN_SHIFT;
    int d = base + t;
    cnt[t] = (d < N) ? rowptr[d] : 0;
    __syncthreads();
    int segLo = histScan[b * NBLK];
    int segHi = (b + 1 < NBINS) ? histScan[(b + 1) * NBLK] : E;
    for (int i = segLo + t; i < segHi; i += 256) {
        int2 en = pairs[i];
        int pos = atomicAdd(&cnt[en.y - base], 1);  // LDS atomic only
        soff[pos] = en.x;
    }
}

// ---- convert fp32 -> fp16 ----
__global__ void cvt_k(const float* __restrict__ in, __half* __restrict__ out, int n) {
    int i = blockIdx.x * blockDim.x + threadIdx.x;
    if (i < n) out[i] = __float2half(in[i]);
}

// ---- c_s/c_d precompute: c4[i] = (W att_src)[i,h], (W att_dst)[i,h] ----
__global__ void prep_c_k(const float* __restrict__ w, const float* __restrict__ att_src,
                         const float* __restrict__ att_dst, float4* __restrict__ c4) {
    int i = threadIdx.x;
    if (i >= DD) return;
    float cs0 = 0.f, cs1 = 0.f, cd0 = 0.f, cd1 = 0.f;
    for (int d = 0; d < DD; d++) {
        float w0 = w[i * (HH * DD) + d], w1 = w[i * (HH * DD) + DD + d];
        cs0 += w0 * att_src[d];
        cs1 += w1 * att_src[DD + d];
        cd0 += w0 * att_dst[d];
        cd1 += w1 * att_dst[DD + d];
    }
    c4[i] = make_float4(cs0, cs1, cd0, cd1);
}

// ---- SAGE fused: gather-mean + lin_l + lin_r + relu -> fp16 (bounded).
// If a_s != nullptr (layer 2): also emit GAT scores from the in-register
// x2 value (saves the separate gat_scores pass). ----
__global__ void sage_fused16(const __half* __restrict__ x, const int* __restrict__ rowptr,
                             const int* __restrict__ soff, const float* __restrict__ wl,
                             const float* __restrict__ bl, const float* __restrict__ wr,
                             __half* __restrict__ out, const float4* __restrict__ c4,
                             float2* __restrict__ a_s, float2* __restrict__ a_d, int N) {
    __shared__ float s_wl[DD * DD];
    __shared__ float s_wr[DD * DD];
    __shared__ float s_b[DD];
    __shared__ float4 s_c[DD];
    for (int i = threadIdx.x; i < DD * DD; i += blockDim.x) {
        s_wl[i] = wl[i];
        s_wr[i] = wr[i];
    }
    if (threadIdx.x < DD) {
        s_b[threadIdx.x] = bl[threadIdx.x];
        if (a_s) s_c[threadIdx.x] = c4[threadIdx.x];
    }
    __syncthreads();
    int gid = blockIdx.x * blockDim.x + threadIdx.x;
    int n = gid >> 5;
    if (n >= N) return;
    int k = gid & 31;
    int lo = rowptr[n], hi = rowptr[n + 1];
    const char* xb = (const char*)x;
    float a0 = 0.f, a1 = 0.f, a2 = 0.f, a3 = 0.f;
    int j = lo;
    for (; j + 3 < hi; j += 4) {
        int o0 = soff[j], o1 = soff[j + 1], o2 = soff[j + 2], o3 = soff[j + 3];
        a0 += __half2float(*(const __half*)(xb + o0 + k * 2));
        a1 += __half2float(*(const __half*)(xb + o1 + k * 2));
        a2 += __half2float(*(const __half*)(xb + o2 + k * 2));
        a3 += __half2float(*(const __half*)(xb + o3 + k * 2));
    }
    for (; j < hi; j++) a0 += __half2float(*(const __half*)(xb + soff[j] + k * 2));
    float mean = ((a0 + a1) + (a2 + a3)) / fmaxf((float)(hi - lo), 1.0f);
    float xv = __half2float(x[n * DD + k]);
    float o = s_b[k];
#pragma unroll
    for (int i = 0; i < DD; i++) {
        o += __shfl(mean, i, 32) * s_wl[i * DD + k];
        o += __shfl(xv, i, 32) * s_wr[i * DD + k];
    }
    o = fmaxf(o, 0.f);
    out[n * DD + k] = __float2half(o);
    if (a_s) {
        float4 c = s_c[k];
        float pa0 = o * c.x, pa1 = o * c.y, pd0 = o * c.z, pd1 = o * c.w;
#pragma unroll
        for (int off = 16; off > 0; off >>= 1) {
            pa0 += __shfl_xor(pa0, off, 32);
            pa1 += __shfl_xor(pa1, off, 32);
            pd0 += __shfl_xor(pd0, off, 32);
            pd1 += __shfl_xor(pd1, off, 32);
        }
        if (k == 0) {
            a_s[n] = make_float2(pa0, pa1);
            a_d[n] = make_float2(pd0, pd1);
        }
    }
}

// ---- GAT aggregate v8: 32 lanes/node, inline softmax weights (edge_w fused:
// a_s is an 800KB L2-resident table, exp chain-free) -> W transform ->
// head-mean+bias+relu -> fused mlp-pre ----
__global__ void gat_agg_v8(const __half* __restrict__ x2, const float2* __restrict__ a_s,
                           const float2* __restrict__ a_d, const int* __restrict__ rowptr,
                           const int* __restrict__ soff, const float* __restrict__ gw,
                           const float* __restrict__ bias, const float* __restrict__ w1,
                           const float* __restrict__ b1, __half* __restrict__ Ps,
                           __half* __restrict__ Pd, int N) {
    __shared__ float s_gw[DD * HH * DD];  // gat W: 32 x 64
    __shared__ float s_w1[2 * DD * DD];   // mlp w1 rows 0..63
    __shared__ float s_b1[DD];
    __shared__ float s_bias[DD];
    int t = threadIdx.x;
    for (int i = t; i < DD * HH * DD; i += blockDim.x) s_gw[i] = gw[i];
    for (int i = t; i < 2 * DD * DD; i += blockDim.x) s_w1[i] = w1[i];
    if (t < DD) {
        s_b1[t] = b1[t];
        s_bias[t] = bias[t];
    }
    __syncthreads();
    int gid = blockIdx.x * blockDim.x + t;
    int n = gid >> 5;
    if (n >= N) return;
    int kk = gid & 31;
    const char* xb = (const char*)x2;
    const char* asb = (const char*)a_s;
    int lo = rowptr[n], hi = rowptr[n + 1];
    float2 as = a_s[n], ad = a_d[n];
    float ws0 = __expf(lrelu(as.x + ad.x));
    float ws1 = __expf(lrelu(as.y + ad.y));
    float xvs = __half2float(x2[n * DD + kk]);
    float den0 = ws0, den1 = ws1;
    float y0a = ws0 * xvs, y1a = ws1 * xvs;
    float y0b = 0.f, y1b = 0.f;
    int j = lo;
    for (; j + 3 < hi; j += 4) {
        int o0 = soff[j], o1 = soff[j + 1], o2 = soff[j + 2], o3 = soff[j + 3];
        float2 s0 = *(const float2*)(asb + (o0 >> 3));
        float2 s1 = *(const float2*)(asb + (o1 >> 3));
        float2 s2 = *(const float2*)(asb + (o2 >> 3));
        float2 s3 = *(const float2*)(asb + (o3 >> 3));
        float xv0 = __half2float(*(const __half*)(xb + o0 + kk * 2));
        float xv1 = __half2float(*(const __half*)(xb + o1 + kk * 2));
        float xv2 = __half2float(*(const __half*)(xb + o2 + kk * 2));
        float xv3 = __half2float(*(const __half*)(xb + o3 + kk * 2));
        float w00 = __expf(lrelu(s0.x + ad.x)), w01 = __expf(lrelu(s0.y + ad.y));
        float w10 = __expf(lrelu(s1.x + ad.x)), w11 = __expf(lrelu(s1.y + ad.y));
        float w20 = __expf(lrelu(s2.x + ad.x)), w21 = __expf(lrelu(s2.y + ad.y));
        float w30 = __expf(lrelu(s3.x + ad.x)), w31 = __expf(lrelu(s3.y + ad.y));
        den0 += (w00 + w10) + (w20 + w30);
        den1 += (w01 + w11) + (w21 + w31);
        y0a += w00 * xv0 + w20 * xv2;
        y1a += w01 * xv0 + w21 * xv2;
        y0b += w10 * xv1 + w30 * xv3;
        y1b += w11 * xv1 + w31 * xv3;
    }
    for (; j < hi; j++) {
        int o0 = soff[j];
        float2 s0 = *(const float2*)(asb + (o0 >> 3));
        float xv0 = __half2float(*(const __half*)(xb + o0 + kk * 2));
        float w00 = __expf(lrelu(s0.x + ad.x)), w01 = __expf(lrelu(s0.y + ad.y));
        den0 += w00;
        den1 += w01;
        y0a += w00 * xv0;
        y1a += w01 * xv0;
    }
    float u0 = (y0a + y0b) / (den0 + 1e-16f);
    float u1 = (y1a + y1b) / (den1 + 1e-16f);
    // out[kk] = 0.5*(u0 @ Wg[:,kk] + u1 @ Wg[:,32+kk]) + bias, relu
    float o = 0.f;
#pragma unroll
    for (int i = 0; i < DD; i++) {
        float c0 = __shfl(u0, i, 32), c1 = __shfl(u1, i, 32);
        o += c0 * s_gw[i * (HH * DD) + kk] + c1 * s_gw[i * (HH * DD) + DD + kk];
    }
    o = fmaxf(0.5f * o + s_bias[kk], 0.f);
    // fused mlp-pre: Ps (rows 0..31 of w1, +b1), Pd (rows 32..63)
    float ps = s_b1[kk], pd = 0.f;
#pragma unroll
    for (int i = 0; i < DD; i++) {
        float oi = __shfl(o, i, 32);
        ps += oi * s_w1[i * DD + kk];
        pd += oi * s_w1[(DD + i) * DD + kk];
    }
    Ps[n * DD + kk] = __float2half(ps);
    Pd[n * DD + kk] = __float2half(pd);
}

// ---- Edge MLP: acc = Ps[s] + Pd[d] + W1e*ea; out = relu(acc) . w2 + b2 ----
// one thread per edge, straight-line body
__device__ __forceinline__ void add_half_row(const __half* __restrict__ row, float acc[DD]) {
    const uint4* r4 = (const uint4*)row;
#pragma unroll
    for (int c = 0; c < 4; c++) {
        uint4 u = r4[c];
        unsigned uu[4] = {u.x, u.y, u.z, u.w};
#pragma unroll
        for (int t = 0; t < 4; t++) {
            __half2 h2 = *reinterpret_cast<const __half2*>(&uu[t]);
            float2 f = __half22float2(h2);
            acc[c * 8 + t * 2 + 0] += f.x;
            acc[c * 8 + t * 2 + 1] += f.y;
        }
    }
}

__global__ void edge_mlp_v3(const __half* __restrict__ Ps, const __half* __restrict__ Pd,
                            const float* __restrict__ eattr, const int* __restrict__ src,
                            const int* __restrict__ dst, const float* __restrict__ w1e,
                            const float* __restrict__ w2, const float* __restrict__ b2,
                            float* __restrict__ out, int E) {
    __shared__ float s_we[EFF * DD];  // rows 64..79 of w1
    __shared__ float s_w2[DD];
    for (int i = threadIdx.x; i < EFF * DD; i += blockDim.x) s_we[i] = w1e[i];
    if (threadIdx.x < DD) s_w2[threadIdx.x] = w2[threadIdx.x];
    __syncthreads();
    int e = blockIdx.x * blockDim.x + threadIdx.x;
    if (e >= E) return;
    float b2v = b2[0];
    int s = src[e], d = dst[e];
    float acc[DD] = {};
    add_half_row(Ps + (size_t)s * DD, acc);
    add_half_row(Pd + (size_t)d * DD, acc);
    const float4* ea4 = (const float4*)(eattr + (size_t)e * EFF);
#pragma unroll
    for (int c = 0; c < 4; c++) {
        float4 v = ea4[c];
        const float va[4] = {v.x, v.y, v.z, v.w};
#pragma unroll
        for (int r = 0; r < 4; r++) {
#pragma unroll
            for (int j4 = 0; j4 < 8; j4++) {
                const float4 w = *(const float4*)(s_we + (c * 4 + r) * DD + j4 * 4);
                acc[j4 * 4 + 0] += va[r] * w.x;
                acc[j4 * 4 + 1] += va[r] * w.y;
                acc[j4 * 4 + 2] += va[r] * w.z;
                acc[j4 * 4 + 3] += va[r] * w.w;
            }
        }
    }
    float p = b2v;
#pragma unroll
    for (int j = 0; j < DD; j++) p += fmaxf(acc[j], 0.f) * s_w2[j];
    out[e] = p;
}

extern "C" void kernel_launch(void* const* d_in, const int* in_sizes, int n_in,
                              void* d_out, int out_size, void* d_ws, size_t ws_size,
                              hipStream_t stream) {
    const int E = in_sizes[0] / 2;
    const int N = in_sizes[2] / DD;

    const int* src = (const int*)d_in[0];
    const int* dst = src + E;
    const float* edge_attr = (const float*)d_in[1];
    const float* node_emb = (const float*)d_in[2];
    const float* sage1_wl = (const float*)d_in[3];
    const float* sage1_bl = (const float*)d_in[4];
    const float* sage1_wr = (const float*)d_in[5];
    const float* sage2_wl = (const float*)d_in[6];
    const float* sage2_bl = (const float*)d_in[7];
    const float* sage2_wr = (const float*)d_in[8];
    const float* gat_w = (const float*)d_in[9];
    const float* gat_att_src = (const float*)d_in[10];
    const float* gat_att_dst = (const float*)d_in[11];
    const float* gat_bias = (const float*)d_in[12];
    const float* mlp_w1 = (const float*)d_in[13];
    const float* mlp_b1 = (const float*)d_in[14];
    const float* mlp_w2 = (const float*)d_in[15];
    const float* mlp_b2 = (const float*)d_in[16];
    float* out = (float*)d_out;

    const int NBINS = (N + 255) >> BIN_SHIFT;          // 391
    const int NBLK = (E + EB - 1) / EB;                // 391
    const int M = NBINS * NBLK;                        // ~153K

    // Workspace layout (256B-aligned chunks)
    char* ws = (char*)d_ws;
    size_t off = 0;
    auto alloc = [&](size_t bytes) {
        char* p = ws + off;
        off = (off + bytes + 255) & ~(size_t)255;
        return p;
    };
    int* deg = (int*)alloc((size_t)N * 4);
    int* rowptr = (int*)alloc((size_t)(N + 1) * 4);
    int* blockSums = (int*)alloc(256 * 4);
    int* dTot = (int*)alloc(4);
    int* soff = (int*)alloc((size_t)E * 4);
    __half* x0h = (__half*)alloc((size_t)N * DD * 2);
    __half* x1h = (__half*)alloc((size_t)N * DD * 2);
    __half* x2h = (__half*)alloc((size_t)N * DD * 2);
    float2* a_s = (float2*)alloc((size_t)N * 8);
    float2* a_d = (float2*)alloc((size_t)N * 8);
    float4* c4 = (float4*)alloc(DD * 16);
    __half* Ps = (__half*)alloc((size_t)N * DD * 2);
    __half* Pd = (__half*)alloc((size_t)N * DD * 2);
    int* histA = (int*)alloc((size_t)M * 4);
    int* histScan = (int*)alloc((size_t)M * 4);
    int2* pairs = (int2*)alloc((size_t)E * 8);

    const int BS = 256;
    const int gE = (E + BS - 1) / BS;
    const int gN32 = (N * 32 + BS - 1) / BS;
    const int gN1 = (N + BS - 1) / BS;
    const int NBn = (N + 1023) / 1024;
    const int NBm = (M + 1023) / 1024;

    // ---- rowptr: degree histogram + scan ----
    hipMemsetAsync(deg, 0, (size_t)N * sizeof(int), stream);
    hist_k<<<gE, BS, 0, stream>>>(dst, deg, E);
    scan1_k<<<NBn, 256, 0, stream>>>(deg, rowptr, blockSums, N);
    scan2_k<<<1, 256, 0, stream>>>(blockSums, rowptr + N, NBn);
    scan3_k<<<gN1, BS, 0, stream>>>(rowptr, blockSums, N);

    // ---- CSR fill: 3-phase counting sort, zero global atomics ----
    radixA_k<<<NBLK, PB_T, 0, stream>>>(dst, histA, E, NBLK, NBINS);
    scan1_k<<<NBm, 256, 0, stream>>>(histA, histScan, blockSums, M);
    scan2_k<<<1, 256, 0, stream>>>(blockSums, dTot, NBm);
    scan3_k<<<(M + BS - 1) / BS, BS, 0, stream>>>(histScan, blockSums, M);
    radixB_k<<<NBLK, PB_T, 0, stream>>>(src, dst, histScan, pairs, E, NBLK, NBINS);
    radixC_k<<<NBINS, 256, 0, stream>>>(rowptr, histScan, pairs, soff, N, NBLK, NBINS, E);

    // ---- fp16 input conversion + attention coefficient vectors ----
    cvt_k<<<gN32, BS, 0, stream>>>(node_emb, x0h, N * DD);
    prep_c_k<<<1, 64, 0, stream>>>(gat_w, gat_att_src, gat_att_dst, c4);

    // ---- SAGE layers (layer 2 also emits GAT scores) ----
    sage_fused16<<<gN32, BS, 0, stream>>>(x0h, rowptr, soff, sage1_wl, sage1_bl, sage1_wr,
                                          x1h, nullptr, nullptr, nullptr, N);
    sage_fused16<<<gN32, BS, 0, stream>>>(x1h, rowptr, soff, sage2_wl, sage2_bl, sage2_wr,
                                          x2h, c4, a_s, a_d, N);

    // ---- GAT aggregate (+ inline softmax weights + fused mlp-pre) ----
    gat_agg_v8<<<gN32, BS, 0, stream>>>(x2h, a_s, a_d, rowptr, soff, gat_w, gat_bias,
                                        mlp_w1, mlp_b1, Ps, Pd, N);

    // ---- Edge MLP ----
    edge_mlp_v3<<<gE, BS, 0, stream>>>(Ps, Pd, edge_attr, src, dst,
                                       mlp_w1 + 2 * DD * DD, mlp_w2, mlp_b2, out, E);
}

// Round 13
// 315.638 us; speedup vs baseline: 2.3492x; 1.5256x over previous
//
#include <hip/hip_runtime.h>
#include <hip/hip_fp16.h>

// GraphSAGE_GAT: SAGE(mean)x2 -> GAT(2 heads, softmax) -> edge MLP
// N=100000, E=1600000, D=32, H=2, EF=16.
// R13: 16 lanes/node (4 nodes/wave) in sage+gat: half2 gathers keep 64B/edge
//      coalescing but halve gather instructions and double edges-in-flight
//      per wave (latency-bound per R12: VALU 56%, HBM 8%). rowptr built
//      inside radixC (bin segment start == rowptr[bin_base]) -> hist_k and
//      the N-scan deleted. Rest = proven R12 kernels.

#define DD 32
#define HH 2
#define EFF 16

#define EB 4096      // edges per radix block
#define PB_T 512     // threads in radix A/B
#define BIN_SHIFT 8  // dst>>8 -> coarse bin (256 nodes/bin)

__device__ __forceinline__ float lrelu(float x) { return x > 0.f ? x : 0.2f * x; }

// ---- generic scan phase 1: per-1024-chunk exclusive scan + chunk totals ----
__global__ void scan1_k(const int* __restrict__ in, int* __restrict__ out,
                        int* __restrict__ blockSums, int M) {
    __shared__ int s_s[256];
    int blk = blockIdx.x, t = threadIdx.x;
    int base = blk * 1024 + t * 4;
    int v[4];
    int s = 0;
#pragma unroll
    for (int i = 0; i < 4; i++) {
        v[i] = (base + i < M) ? in[base + i] : 0;
        s += v[i];
    }
    s_s[t] = s;
    __syncthreads();
    for (int off = 1; off < 256; off <<= 1) {
        int x = (t >= off) ? s_s[t - off] : 0;
        __syncthreads();
        s_s[t] += x;
        __syncthreads();
    }
    int excl = s_s[t] - s;
#pragma unroll
    for (int i = 0; i < 4; i++) {
        if (base + i < M) out[base + i] = excl;
        excl += v[i];
    }
    if (t == 255) blockSums[blk] = s_s[255];
}

// ---- generic scan phase 2: scan the chunk totals (<=256 chunks) ----
__global__ void scan2_k(int* __restrict__ blockSums, int* __restrict__ totalOut, int NB) {
    __shared__ int s_s[256];
    int t = threadIdx.x;
    int v = (t < NB) ? blockSums[t] : 0;
    s_s[t] = v;
    __syncthreads();
    for (int off = 1; off < 256; off <<= 1) {
        int x = (t >= off) ? s_s[t - off] : 0;
        __syncthreads();
        s_s[t] += x;
        __syncthreads();
    }
    if (t < NB) blockSums[t] = s_s[t] - v;  // exclusive
    if (t == 255) *totalOut = s_s[255];
}

// ---- generic scan phase 3: add chunk offsets ----
__global__ void scan3_k(int* __restrict__ out, const int* __restrict__ blockSums, int M) {
    int i = blockIdx.x * blockDim.x + threadIdx.x;
    if (i < M) out[i] += blockSums[i >> 10];
}

// ---- radix A: per-block coarse histogram (bin = dst>>8), LDS only ----
__global__ void radixA_k(const int* __restrict__ dst, int* __restrict__ histA, int E,
                         int NBLK, int NBINS) {
    __shared__ int s_h[512];
    int blk = blockIdx.x, t = threadIdx.x;
    for (int b = t; b < 512; b += PB_T) s_h[b] = 0;
    __syncthreads();
    int e0 = blk * EB;
    for (int i = t; i < EB; i += PB_T) {
        int e = e0 + i;
        if (e < E) atomicAdd(&s_h[dst[e] >> BIN_SHIFT], 1);
    }
    __syncthreads();
    for (int b = t; b < NBINS; b += PB_T) histA[b * NBLK + blk] = s_h[b];
}

// ---- radix B: place (src*64,dst) into this block's private window per bin ----
__global__ void radixB_k(const int* __restrict__ src, const int* __restrict__ dst,
                         const int* __restrict__ histScan, int2* __restrict__ pairs,
                         int E, int NBLK, int NBINS) {
    __shared__ int s_base[512];
    int blk = blockIdx.x, t = threadIdx.x;
    for (int b = t; b < NBINS; b += PB_T) s_base[b] = histScan[b * NBLK + blk];
    __syncthreads();
    int e0 = blk * EB;
    for (int i = t; i < EB; i += PB_T) {
        int e = e0 + i;
        if (e < E) {
            int d = dst[e];
            int pos = atomicAdd(&s_base[d >> BIN_SHIFT], 1);  // LDS atomic only
            pairs[pos] = make_int2(src[e] * 64, d);
        }
    }
}

// ---- radix C v2: one block per bin. Builds rowptr for its 256 nodes
// (count -> local scan, seeded by the bin's segment start which IS the
// bin-base rowptr) and scatters soff within the bin's contiguous window. ----
__global__ void radixC_v2(const int* __restrict__ histScan, const int2* __restrict__ pairs,
                          int* __restrict__ rowptr, int* __restrict__ soff, int N,
                          int NBLK, int NBINS, int E) {
    __shared__ int cnt[256];
    __shared__ int scanBuf[256];
    __shared__ int basePos[256];
    int b = blockIdx.x, t = threadIdx.x;
    int base = b << BIN_SHIFT;
    cnt[t] = 0;
    __syncthreads();
    int segLo = histScan[b * NBLK];
    int segHi = (b + 1 < NBINS) ? histScan[(b + 1) * NBLK] : E;
    for (int i = segLo + t; i < segHi; i += 256) atomicAdd(&cnt[pairs[i].y - base], 1);
    __syncthreads();
    int v = cnt[t];
    scanBuf[t] = v;
    __syncthreads();
    for (int off = 1; off < 256; off <<= 1) {
        int x = (t >= off) ? scanBuf[t - off] : 0;
        __syncthreads();
        scanBuf[t] += x;
        __syncthreads();
    }
    int excl = segLo + scanBuf[t] - v;  // exclusive scan + segment base
    basePos[t] = excl;
    if (base + t < N) rowptr[base + t] = excl;
    if (b == NBINS - 1 && t == 0) rowptr[N] = E;
    __syncthreads();
    for (int i = segLo + t; i < segHi; i += 256) {
        int2 en = pairs[i];
        int pos = atomicAdd(&basePos[en.y - base], 1);  // LDS atomic only
        soff[pos] = en.x;
    }
}

// ---- convert fp32 -> fp16 ----
__global__ void cvt_k(const float* __restrict__ in, __half* __restrict__ out, int n) {
    int i = blockIdx.x * blockDim.x + threadIdx.x;
    if (i < n) out[i] = __float2half(in[i]);
}

// ---- c_s/c_d precompute: c4[i] = (W att_src)[i,h], (W att_dst)[i,h] ----
__global__ void prep_c_k(const float* __restrict__ w, const float* __restrict__ att_src,
                         const float* __restrict__ att_dst, float4* __restrict__ c4) {
    int i = threadIdx.x;
    if (i >= DD) return;
    float cs0 = 0.f, cs1 = 0.f, cd0 = 0.f, cd1 = 0.f;
    for (int d = 0; d < DD; d++) {
        float w0 = w[i * (HH * DD) + d], w1 = w[i * (HH * DD) + DD + d];
        cs0 += w0 * att_src[d];
        cs1 += w1 * att_src[DD + d];
        cd0 += w0 * att_dst[d];
        cd1 += w1 * att_dst[DD + d];
    }
    c4[i] = make_float4(cs0, cs1, cd0, cd1);
}

// ---- SAGE fused v2: 16 lanes/node (features 2l,2l+1 as half2/float2).
// Gather-mean + lin_l + lin_r + relu -> fp16. Layer 2 (a_s!=null) also
// emits GAT scores from the in-register output. ----
__global__ void sage16x4_k(const __half* __restrict__ x, const int* __restrict__ rowptr,
                           const int* __restrict__ soff, const float* __restrict__ wl,
                           const float* __restrict__ bl, const float* __restrict__ wr,
                           __half* __restrict__ out, const float4* __restrict__ c4,
                           float2* __restrict__ a_s, float2* __restrict__ a_d, int N) {
    __shared__ float s_wl[DD * DD];
    __shared__ float s_wr[DD * DD];
    __shared__ float s_b[DD];
    __shared__ float4 s_c[DD];
    for (int i = threadIdx.x; i < DD * DD; i += blockDim.x) {
        s_wl[i] = wl[i];
        s_wr[i] = wr[i];
    }
    if (threadIdx.x < DD) {
        s_b[threadIdx.x] = bl[threadIdx.x];
        if (a_s) s_c[threadIdx.x] = c4[threadIdx.x];
    }
    __syncthreads();
    int gid = blockIdx.x * blockDim.x + threadIdx.x;
    int n = gid >> 4;
    if (n >= N) return;
    int l = gid & 15;
    int lo = rowptr[n], hi = rowptr[n + 1];
    const char* xb = (const char*)x;
    float ax0 = 0.f, ay0 = 0.f, ax1 = 0.f, ay1 = 0.f;
    float ax2 = 0.f, ay2 = 0.f, ax3 = 0.f, ay3 = 0.f;
    int j = lo;
    for (; j + 3 < hi; j += 4) {
        int o0 = soff[j], o1 = soff[j + 1], o2 = soff[j + 2], o3 = soff[j + 3];
        float2 v0 = __half22float2(*(const __half2*)(xb + o0 + l * 4));
        float2 v1 = __half22float2(*(const __half2*)(xb + o1 + l * 4));
        float2 v2 = __half22float2(*(const __half2*)(xb + o2 + l * 4));
        float2 v3 = __half22float2(*(const __half2*)(xb + o3 + l * 4));
        ax0 += v0.x; ay0 += v0.y;
        ax1 += v1.x; ay1 += v1.y;
        ax2 += v2.x; ay2 += v2.y;
        ax3 += v3.x; ay3 += v3.y;
    }
    for (; j < hi; j++) {
        float2 v0 = __half22float2(*(const __half2*)(xb + soff[j] + l * 4));
        ax0 += v0.x; ay0 += v0.y;
    }
    float inv = 1.0f / fmaxf((float)(hi - lo), 1.0f);
    float mx = ((ax0 + ax1) + (ax2 + ax3)) * inv;
    float my = ((ay0 + ay1) + (ay2 + ay3)) * inv;
    float2 xv = __half22float2(*(const __half2*)(xb + (size_t)n * 64 + l * 4));
    float accx = s_b[2 * l], accy = s_b[2 * l + 1];
#pragma unroll
    for (int i2 = 0; i2 < 16; i2++) {
        float bmx = __shfl(mx, i2, 16), bmy = __shfl(my, i2, 16);
        float bxx = __shfl(xv.x, i2, 16), bxy = __shfl(xv.y, i2, 16);
        float2 wl0 = *(const float2*)(s_wl + (2 * i2) * DD + 2 * l);
        float2 wl1 = *(const float2*)(s_wl + (2 * i2 + 1) * DD + 2 * l);
        float2 wr0 = *(const float2*)(s_wr + (2 * i2) * DD + 2 * l);
        float2 wr1 = *(const float2*)(s_wr + (2 * i2 + 1) * DD + 2 * l);
        accx += bmx * wl0.x + bmy * wl1.x + bxx * wr0.x + bxy * wr1.x;
        accy += bmx * wl0.y + bmy * wl1.y + bxx * wr0.y + bxy * wr1.y;
    }
    accx = fmaxf(accx, 0.f);
    accy = fmaxf(accy, 0.f);
    *(__half2*)(out + (size_t)n * DD + 2 * l) = __floats2half2_rn(accx, accy);
    if (a_s) {
        float4 c0 = s_c[2 * l], c1 = s_c[2 * l + 1];
        float pa0 = accx * c0.x + accy * c1.x;
        float pa1 = accx * c0.y + accy * c1.y;
        float pd0 = accx * c0.z + accy * c1.z;
        float pd1 = accx * c0.w + accy * c1.w;
#pragma unroll
        for (int off = 8; off > 0; off >>= 1) {
            pa0 += __shfl_xor(pa0, off, 16);
            pa1 += __shfl_xor(pa1, off, 16);
            pd0 += __shfl_xor(pd0, off, 16);
            pd1 += __shfl_xor(pd1, off, 16);
        }
        if (l == 0) {
            a_s[n] = make_float2(pa0, pa1);
            a_d[n] = make_float2(pd0, pd1);
        }
    }
}

// ---- GAT aggregate v9: 16 lanes/node, inline softmax weights, half2 gathers
// -> W transform -> head-mean+bias+relu -> fused mlp-pre ----
__global__ void gat_agg_v9(const __half* __restrict__ x2, const float2* __restrict__ a_s,
                           const float2* __restrict__ a_d, const int* __restrict__ rowptr,
                           const int* __restrict__ soff, const float* __restrict__ gw,
                           const float* __restrict__ bias, const float* __restrict__ w1,
                           const float* __restrict__ b1, __half* __restrict__ Ps,
                           __half* __restrict__ Pd, int N) {
    __shared__ float s_gw[DD * HH * DD];  // gat W: 32 x 64
    __shared__ float s_w1[2 * DD * DD];   // mlp w1 rows 0..63
    __shared__ float s_b1[DD];
    __shared__ float s_bias[DD];
    int t = threadIdx.x;
    for (int i = t; i < DD * HH * DD; i += blockDim.x) s_gw[i] = gw[i];
    for (int i = t; i < 2 * DD * DD; i += blockDim.x) s_w1[i] = w1[i];
    if (t < DD) {
        s_b1[t] = b1[t];
        s_bias[t] = bias[t];
    }
    __syncthreads();
    int gid = blockIdx.x * blockDim.x + t;
    int n = gid >> 4;
    if (n >= N) return;
    int l = gid & 15;
    const char* xb = (const char*)x2;
    const char* asb = (const char*)a_s;
    int lo = rowptr[n], hi = rowptr[n + 1];
    float2 as = a_s[n], ad = a_d[n];
    float ws0 = __expf(lrelu(as.x + ad.x));
    float ws1 = __expf(lrelu(as.y + ad.y));
    float2 xvs = __half22float2(*(const __half2*)(xb + (size_t)n * 64 + l * 4));
    float den0 = ws0, den1 = ws1;
    float y0x = ws0 * xvs.x, y0y = ws0 * xvs.y;
    float y1x = ws1 * xvs.x, y1y = ws1 * xvs.y;
    int j = lo;
    for (; j + 3 < hi; j += 4) {
        int o0 = soff[j], o1 = soff[j + 1], o2 = soff[j + 2], o3 = soff[j + 3];
        float2 s0 = *(const float2*)(asb + (o0 >> 3));
        float2 s1 = *(const float2*)(asb + (o1 >> 3));
        float2 s2 = *(const float2*)(asb + (o2 >> 3));
        float2 s3 = *(const float2*)(asb + (o3 >> 3));
        float2 v0 = __half22float2(*(const __half2*)(xb + o0 + l * 4));
        float2 v1 = __half22float2(*(const __half2*)(xb + o1 + l * 4));
        float2 v2 = __half22float2(*(const __half2*)(xb + o2 + l * 4));
        float2 v3 = __half22float2(*(const __half2*)(xb + o3 + l * 4));
        float w00 = __expf(lrelu(s0.x + ad.x)), w01 = __expf(lrelu(s0.y + ad.y));
        float w10 = __expf(lrelu(s1.x + ad.x)), w11 = __expf(lrelu(s1.y + ad.y));
        float w20 = __expf(lrelu(s2.x + ad.x)), w21 = __expf(lrelu(s2.y + ad.y));
        float w30 = __expf(lrelu(s3.x + ad.x)), w31 = __expf(lrelu(s3.y + ad.y));
        den0 += (w00 + w10) + (w20 + w30);
        den1 += (w01 + w11) + (w21 + w31);
        y0x += w00 * v0.x + w10 * v1.x + w20 * v2.x + w30 * v3.x;
        y0y += w00 * v0.y + w10 * v1.y + w20 * v2.y + w30 * v3.y;
        y1x += w01 * v0.x + w11 * v1.x + w21 * v2.x + w31 * v3.x;
        y1y += w01 * v0.y + w11 * v1.y + w21 * v2.y + w31 * v3.y;
    }
    for (; j < hi; j++) {
        int o0 = soff[j];
        float2 s0 = *(const float2*)(asb + (o0 >> 3));
        float2 v0 = __half22float2(*(const __half2*)(xb + o0 + l * 4));
        float w00 = __expf(lrelu(s0.x + ad.x)), w01 = __expf(lrelu(s0.y + ad.y));
        den0 += w00;
        den1 += w01;
        y0x += w00 * v0.x;
        y0y += w00 * v0.y;
        y1x += w01 * v0.x;
        y1y += w01 * v0.y;
    }
    float i0 = 1.0f / (den0 + 1e-16f), i1 = 1.0f / (den1 + 1e-16f);
    float u0x = y0x * i0, u0y = y0y * i0;
    float u1x = y1x * i1, u1y = y1y * i1;
    // o[f] = 0.5*(sum_i u0[i] gw[i][f] + u1[i] gw[i][32+f]) + bias, relu
    float ox = 0.f, oy = 0.f;
#pragma unroll
    for (int i2 = 0; i2 < 16; i2++) {
        float b0x = __shfl(u0x, i2, 16), b0y = __shfl(u0y, i2, 16);
        float b1x = __shfl(u1x, i2, 16), b1y = __shfl(u1y, i2, 16);
        float2 g00 = *(const float2*)(s_gw + (2 * i2) * (HH * DD) + 2 * l);
        float2 g01 = *(const float2*)(s_gw + (2 * i2 + 1) * (HH * DD) + 2 * l);
        float2 g10 = *(const float2*)(s_gw + (2 * i2) * (HH * DD) + DD + 2 * l);
        float2 g11 = *(const float2*)(s_gw + (2 * i2 + 1) * (HH * DD) + DD + 2 * l);
        ox += b0x * g00.x + b0y * g01.x + b1x * g10.x + b1y * g11.x;
        oy += b0x * g00.y + b0y * g01.y + b1x * g10.y + b1y * g11.y;
    }
    ox = fmaxf(0.5f * ox + s_bias[2 * l], 0.f);
    oy = fmaxf(0.5f * oy + s_bias[2 * l + 1], 0.f);
    // fused mlp-pre: Ps (rows 0..31 of w1, +b1), Pd (rows 32..63)
    float psx = s_b1[2 * l], psy = s_b1[2 * l + 1];
    float pdx = 0.f, pdy = 0.f;
#pragma unroll
    for (int i2 = 0; i2 < 16; i2++) {
        float box = __shfl(ox, i2, 16), boy = __shfl(oy, i2, 16);
        float2 wa0 = *(const float2*)(s_w1 + (2 * i2) * DD + 2 * l);
        float2 wa1 = *(const float2*)(s_w1 + (2 * i2 + 1) * DD + 2 * l);
        float2 wb0 = *(const float2*)(s_w1 + (DD + 2 * i2) * DD + 2 * l);
        float2 wb1 = *(const float2*)(s_w1 + (DD + 2 * i2 + 1) * DD + 2 * l);
        psx += box * wa0.x + boy * wa1.x;
        psy += box * wa0.y + boy * wa1.y;
        pdx += box * wb0.x + boy * wb1.x;
        pdy += box * wb0.y + boy * wb1.y;
    }
    *(__half2*)(Ps + (size_t)n * DD + 2 * l) = __floats2half2_rn(psx, psy);
    *(__half2*)(Pd + (size_t)n * DD + 2 * l) = __floats2half2_rn(pdx, pdy);
}

// ---- Edge MLP: acc = Ps[s] + Pd[d] + W1e*ea; out = relu(acc) . w2 + b2 ----
// one thread per edge, straight-line body
__device__ __forceinline__ void add_half_row(const __half* __restrict__ row, float acc[DD]) {
    const uint4* r4 = (const uint4*)row;
#pragma unroll
    for (int c = 0; c < 4; c++) {
        uint4 u = r4[c];
        unsigned uu[4] = {u.x, u.y, u.z, u.w};
#pragma unroll
        for (int t = 0; t < 4; t++) {
            __half2 h2 = *reinterpret_cast<const __half2*>(&uu[t]);
            float2 f = __half22float2(h2);
            acc[c * 8 + t * 2 + 0] += f.x;
            acc[c * 8 + t * 2 + 1] += f.y;
        }
    }
}

__global__ void edge_mlp_v3(const __half* __restrict__ Ps, const __half* __restrict__ Pd,
                            const float* __restrict__ eattr, const int* __restrict__ src,
                            const int* __restrict__ dst, const float* __restrict__ w1e,
                            const float* __restrict__ w2, const float* __restrict__ b2,
                            float* __restrict__ out, int E) {
    __shared__ float s_we[EFF * DD];  // rows 64..79 of w1
    __shared__ float s_w2[DD];
    for (int i = threadIdx.x; i < EFF * DD; i += blockDim.x) s_we[i] = w1e[i];
    if (threadIdx.x < DD) s_w2[threadIdx.x] = w2[threadIdx.x];
    __syncthreads();
    int e = blockIdx.x * blockDim.x + threadIdx.x;
    if (e >= E) return;
    float b2v = b2[0];
    int s = src[e], d = dst[e];
    float acc[DD] = {};
    add_half_row(Ps + (size_t)s * DD, acc);
    add_half_row(Pd + (size_t)d * DD, acc);
    const float4* ea4 = (const float4*)(eattr + (size_t)e * EFF);
#pragma unroll
    for (int c = 0; c < 4; c++) {
        float4 v = ea4[c];
        const float va[4] = {v.x, v.y, v.z, v.w};
#pragma unroll
        for (int r = 0; r < 4; r++) {
#pragma unroll
            for (int j4 = 0; j4 < 8; j4++) {
                const float4 w = *(const float4*)(s_we + (c * 4 + r) * DD + j4 * 4);
                acc[j4 * 4 + 0] += va[r] * w.x;
                acc[j4 * 4 + 1] += va[r] * w.y;
                acc[j4 * 4 + 2] += va[r] * w.z;
                acc[j4 * 4 + 3] += va[r] * w.w;
            }
        }
    }
    float p = b2v;
#pragma unroll
    for (int j = 0; j < DD; j++) p += fmaxf(acc[j], 0.f) * s_w2[j];
    out[e] = p;
}

extern "C" void kernel_launch(void* const* d_in, const int* in_sizes, int n_in,
                              void* d_out, int out_size, void* d_ws, size_t ws_size,
                              hipStream_t stream) {
    const int E = in_sizes[0] / 2;
    const int N = in_sizes[2] / DD;

    const int* src = (const int*)d_in[0];
    const int* dst = src + E;
    const float* edge_attr = (const float*)d_in[1];
    const float* node_emb = (const float*)d_in[2];
    const float* sage1_wl = (const float*)d_in[3];
    const float* sage1_bl = (const float*)d_in[4];
    const float* sage1_wr = (const float*)d_in[5];
    const float* sage2_wl = (const float*)d_in[6];
    const float* sage2_bl = (const float*)d_in[7];
    const float* sage2_wr = (const float*)d_in[8];
    const float* gat_w = (const float*)d_in[9];
    const float* gat_att_src = (const float*)d_in[10];
    const float* gat_att_dst = (const float*)d_in[11];
    const float* gat_bias = (const float*)d_in[12];
    const float* mlp_w1 = (const float*)d_in[13];
    const float* mlp_b1 = (const float*)d_in[14];
    const float* mlp_w2 = (const float*)d_in[15];
    const float* mlp_b2 = (const float*)d_in[16];
    float* out = (float*)d_out;

    const int NBINS = (N + 255) >> BIN_SHIFT;
    const int NBLK = (E + EB - 1) / EB;
    const int M = NBINS * NBLK;

    // Workspace layout (256B-aligned chunks)
    char* ws = (char*)d_ws;
    size_t off = 0;
    auto alloc = [&](size_t bytes) {
        char* p = ws + off;
        off = (off + bytes + 255) & ~(size_t)255;
        return p;
    };
    int* rowptr = (int*)alloc((size_t)(N + 1) * 4);
    int* blockSums = (int*)alloc(256 * 4);
    int* dTot = (int*)alloc(4);
    int* soff = (int*)alloc((size_t)E * 4);
    __half* x0h = (__half*)alloc((size_t)N * DD * 2);
    __half* x1h = (__half*)alloc((size_t)N * DD * 2);
    __half* x2h = (__half*)alloc((size_t)N * DD * 2);
    float2* a_s = (float2*)alloc((size_t)N * 8);
    float2* a_d = (float2*)alloc((size_t)N * 8);
    float4* c4 = (float4*)alloc(DD * 16);
    __half* Ps = (__half*)alloc((size_t)N * DD * 2);
    __half* Pd = (__half*)alloc((size_t)N * DD * 2);
    int* histA = (int*)alloc((size_t)M * 4);
    int* histScan = (int*)alloc((size_t)M * 4);
    int2* pairs = (int2*)alloc((size_t)E * 8);

    const int BS = 256;
    const int gE = (E + BS - 1) / BS;
    const int gN32 = (N * 32 + BS - 1) / BS;
    const int gN16 = (N * 16 + BS - 1) / BS;
    const int NBm = (M + 1023) / 1024;

    // ---- CSR build: counting sort; rowptr built inside radixC ----
    radixA_k<<<NBLK, PB_T, 0, stream>>>(dst, histA, E, NBLK, NBINS);
    scan1_k<<<NBm, 256, 0, stream>>>(histA, histScan, blockSums, M);
    scan2_k<<<1, 256, 0, stream>>>(blockSums, dTot, NBm);
    scan3_k<<<(M + BS - 1) / BS, BS, 0, stream>>>(histScan, blockSums, M);
    radixB_k<<<NBLK, PB_T, 0, stream>>>(src, dst, histScan, pairs, E, NBLK, NBINS);
    radixC_v2<<<NBINS, 256, 0, stream>>>(histScan, pairs, rowptr, soff, N, NBLK, NBINS, E);

    // ---- fp16 input conversion + attention coefficient vectors ----
    cvt_k<<<gN32, BS, 0, stream>>>(node_emb, x0h, N * DD);
    prep_c_k<<<1, 64, 0, stream>>>(gat_w, gat_att_src, gat_att_dst, c4);

    // ---- SAGE layers (layer 2 also emits GAT scores) ----
    sage16x4_k<<<gN16, BS, 0, stream>>>(x0h, rowptr, soff, sage1_wl, sage1_bl, sage1_wr,
                                        x1h, nullptr, nullptr, nullptr, N);
    sage16x4_k<<<gN16, BS, 0, stream>>>(x1h, rowptr, soff, sage2_wl, sage2_bl, sage2_wr,
                                        x2h, c4, a_s, a_d, N);

    // ---- GAT aggregate (+ inline softmax weights + fused mlp-pre) ----
    gat_agg_v9<<<gN16, BS, 0, stream>>>(x2h, a_s, a_d, rowptr, soff, gat_w, gat_bias,
                                        mlp_w1, mlp_b1, Ps, Pd, N);

    // ---- Edge MLP ----
    edge_mlp_v3<<<gE, BS, 0, stream>>>(Ps, Pd, edge_attr, src, dst,
                                       mlp_w1 + 2 * DD * DD, mlp_w2, mlp_b2, out, E);
}

// Round 14
// 253.301 us; speedup vs baseline: 2.9273x; 1.2461x over previous
//
#include <hip/hip_runtime.h>
#include <hip/hip_fp16.h>

// GraphSAGE_GAT: SAGE(mean)x2 -> GAT(2 heads, softmax) -> edge MLP
// N=100000, E=1600000, D=32, H=2, EF=16.
// R14: 8 lanes/node (8 nodes/wave) in sage+gat: half4 (uint2) gathers keep
//      64B/edge coalescing, halve instructions/edge again, double edges in
//      flight (R13's 16-lane move gave -34% on the same theory). Redundant
//      per-edge exp now x8 not x16. pairs packed int2->int ((src<<8)|dloc):
//      radixB write + radixC read halved. Rest = proven R13 structure.

#define DD 32
#define HH 2
#define EFF 16

#define EB 4096      // edges per radix block
#define PB_T 512     // threads in radix A/B
#define BIN_SHIFT 8  // dst>>8 -> coarse bin (256 nodes/bin)

__device__ __forceinline__ float lrelu(float x) { return x > 0.f ? x : 0.2f * x; }

// ---- generic scan phase 1: per-1024-chunk exclusive scan + chunk totals ----
__global__ void scan1_k(const int* __restrict__ in, int* __restrict__ out,
                        int* __restrict__ blockSums, int M) {
    __shared__ int s_s[256];
    int blk = blockIdx.x, t = threadIdx.x;
    int base = blk * 1024 + t * 4;
    int v[4];
    int s = 0;
#pragma unroll
    for (int i = 0; i < 4; i++) {
        v[i] = (base + i < M) ? in[base + i] : 0;
        s += v[i];
    }
    s_s[t] = s;
    __syncthreads();
    for (int off = 1; off < 256; off <<= 1) {
        int x = (t >= off) ? s_s[t - off] : 0;
        __syncthreads();
        s_s[t] += x;
        __syncthreads();
    }
    int excl = s_s[t] - s;
#pragma unroll
    for (int i = 0; i < 4; i++) {
        if (base + i < M) out[base + i] = excl;
        excl += v[i];
    }
    if (t == 255) blockSums[blk] = s_s[255];
}

// ---- generic scan phase 2: scan the chunk totals (<=256 chunks) ----
__global__ void scan2_k(int* __restrict__ blockSums, int* __restrict__ totalOut, int NB) {
    __shared__ int s_s[256];
    int t = threadIdx.x;
    int v = (t < NB) ? blockSums[t] : 0;
    s_s[t] = v;
    __syncthreads();
    for (int off = 1; off < 256; off <<= 1) {
        int x = (t >= off) ? s_s[t - off] : 0;
        __syncthreads();
        s_s[t] += x;
        __syncthreads();
    }
    if (t < NB) blockSums[t] = s_s[t] - v;  // exclusive
    if (t == 255) *totalOut = s_s[255];
}

// ---- generic scan phase 3: add chunk offsets ----
__global__ void scan3_k(int* __restrict__ out, const int* __restrict__ blockSums, int M) {
    int i = blockIdx.x * blockDim.x + threadIdx.x;
    if (i < M) out[i] += blockSums[i >> 10];
}

// ---- radix A: per-block coarse histogram (bin = dst>>8), LDS only ----
__global__ void radixA_k(const int* __restrict__ dst, int* __restrict__ histA, int E,
                         int NBLK, int NBINS) {
    __shared__ int s_h[512];
    int blk = blockIdx.x, t = threadIdx.x;
    for (int b = t; b < 512; b += PB_T) s_h[b] = 0;
    __syncthreads();
    int e0 = blk * EB;
    for (int i = t; i < EB; i += PB_T) {
        int e = e0 + i;
        if (e < E) atomicAdd(&s_h[dst[e] >> BIN_SHIFT], 1);
    }
    __syncthreads();
    for (int b = t; b < NBINS; b += PB_T) histA[b * NBLK + blk] = s_h[b];
}

// ---- radix B: place packed (src<<8)|dloc into block's private window ----
__global__ void radixB_k(const int* __restrict__ src, const int* __restrict__ dst,
                         const int* __restrict__ histScan, int* __restrict__ pairs,
                         int E, int NBLK, int NBINS) {
    __shared__ int s_base[512];
    int blk = blockIdx.x, t = threadIdx.x;
    for (int b = t; b < NBINS; b += PB_T) s_base[b] = histScan[b * NBLK + blk];
    __syncthreads();
    int e0 = blk * EB;
    for (int i = t; i < EB; i += PB_T) {
        int e = e0 + i;
        if (e < E) {
            int d = dst[e];
            int pos = atomicAdd(&s_base[d >> BIN_SHIFT], 1);  // LDS atomic only
            pairs[pos] = (src[e] << 8) | (d & 255);
        }
    }
}

// ---- radix C v2: one block per bin. Builds rowptr for its 256 nodes and
// scatters soff within the bin's contiguous window. pairs are packed ints. ----
__global__ void radixC_v2(const int* __restrict__ histScan, const int* __restrict__ pairs,
                          int* __restrict__ rowptr, int* __restrict__ soff, int N,
                          int NBLK, int NBINS, int E) {
    __shared__ int cnt[256];
    __shared__ int scanBuf[256];
    __shared__ int basePos[256];
    int b = blockIdx.x, t = threadIdx.x;
    int base = b << BIN_SHIFT;
    cnt[t] = 0;
    __syncthreads();
    int segLo = histScan[b * NBLK];
    int segHi = (b + 1 < NBINS) ? histScan[(b + 1) * NBLK] : E;
    for (int i = segLo + t; i < segHi; i += 256) atomicAdd(&cnt[pairs[i] & 255], 1);
    __syncthreads();
    int v = cnt[t];
    scanBuf[t] = v;
    __syncthreads();
    for (int off = 1; off < 256; off <<= 1) {
        int x = (t >= off) ? scanBuf[t - off] : 0;
        __syncthreads();
        scanBuf[t] += x;
        __syncthreads();
    }
    int excl = segLo + scanBuf[t] - v;  // exclusive scan + segment base
    basePos[t] = excl;
    if (base + t < N) rowptr[base + t] = excl;
    if (b == NBINS - 1 && t == 0) rowptr[N] = E;
    __syncthreads();
    for (int i = segLo + t; i < segHi; i += 256) {
        int en = pairs[i];
        int pos = atomicAdd(&basePos[en & 255], 1);  // LDS atomic only
        soff[pos] = (en >> 8) << 6;                  // src*64
    }
}

// ---- convert fp32 -> fp16 ----
__global__ void cvt_k(const float* __restrict__ in, __half* __restrict__ out, int n) {
    int i = blockIdx.x * blockDim.x + threadIdx.x;
    if (i < n) out[i] = __float2half(in[i]);
}

// ---- c_s/c_d precompute: c4[i] = (W att_src)[i,h], (W att_dst)[i,h] ----
__global__ void prep_c_k(const float* __restrict__ w, const float* __restrict__ att_src,
                         const float* __restrict__ att_dst, float4* __restrict__ c4) {
    int i = threadIdx.x;
    if (i >= DD) return;
    float cs0 = 0.f, cs1 = 0.f, cd0 = 0.f, cd1 = 0.f;
    for (int d = 0; d < DD; d++) {
        float w0 = w[i * (HH * DD) + d], w1 = w[i * (HH * DD) + DD + d];
        cs0 += w0 * att_src[d];
        cs1 += w1 * att_src[DD + d];
        cd0 += w0 * att_dst[d];
        cd1 += w1 * att_dst[DD + d];
    }
    c4[i] = make_float4(cs0, cs1, cd0, cd1);
}

__device__ __forceinline__ void unpack4(unsigned lo, unsigned hi, float f[4]) {
    float2 a = __half22float2(*reinterpret_cast<const __half2*>(&lo));
    float2 b = __half22float2(*reinterpret_cast<const __half2*>(&hi));
    f[0] = a.x; f[1] = a.y; f[2] = b.x; f[3] = b.y;
}

// ---- SAGE fused v3: 8 lanes/node (features 4l..4l+3 as half4/uint2).
// Gather-mean + lin_l + lin_r + relu -> fp16. Layer 2 (a_s!=null) also
// emits GAT scores from the in-register output. ----
__global__ void sage8x8_k(const __half* __restrict__ x, const int* __restrict__ rowptr,
                          const int* __restrict__ soff, const float* __restrict__ wl,
                          const float* __restrict__ bl, const float* __restrict__ wr,
                          __half* __restrict__ out, const float4* __restrict__ c4,
                          float2* __restrict__ a_s, float2* __restrict__ a_d, int N) {
    __shared__ float s_wl[DD * DD];
    __shared__ float s_wr[DD * DD];
    __shared__ float s_b[DD];
    __shared__ float4 s_c[DD];
    for (int i = threadIdx.x; i < DD * DD; i += blockDim.x) {
        s_wl[i] = wl[i];
        s_wr[i] = wr[i];
    }
    if (threadIdx.x < DD) {
        s_b[threadIdx.x] = bl[threadIdx.x];
        if (a_s) s_c[threadIdx.x] = c4[threadIdx.x];
    }
    __syncthreads();
    int gid = blockIdx.x * blockDim.x + threadIdx.x;
    int n = gid >> 3;
    if (n >= N) return;
    int l = gid & 7;
    int lo = rowptr[n], hi = rowptr[n + 1];
    const char* xb = (const char*)x;
    float acc[4] = {0.f, 0.f, 0.f, 0.f};
    int j = lo;
    for (; j + 3 < hi; j += 4) {
        int o0 = soff[j], o1 = soff[j + 1], o2 = soff[j + 2], o3 = soff[j + 3];
        uint2 r0 = *(const uint2*)(xb + o0 + l * 8);
        uint2 r1 = *(const uint2*)(xb + o1 + l * 8);
        uint2 r2 = *(const uint2*)(xb + o2 + l * 8);
        uint2 r3 = *(const uint2*)(xb + o3 + l * 8);
        float v0[4], v1[4], v2[4], v3[4];
        unpack4(r0.x, r0.y, v0);
        unpack4(r1.x, r1.y, v1);
        unpack4(r2.x, r2.y, v2);
        unpack4(r3.x, r3.y, v3);
#pragma unroll
        for (int f = 0; f < 4; f++) acc[f] += (v0[f] + v1[f]) + (v2[f] + v3[f]);
    }
    for (; j < hi; j++) {
        uint2 r0 = *(const uint2*)(xb + soff[j] + l * 8);
        float v0[4];
        unpack4(r0.x, r0.y, v0);
#pragma unroll
        for (int f = 0; f < 4; f++) acc[f] += v0[f];
    }
    float inv = 1.0f / fmaxf((float)(hi - lo), 1.0f);
    float mx[4];
#pragma unroll
    for (int f = 0; f < 4; f++) mx[f] = acc[f] * inv;
    uint2 sr = *(const uint2*)(xb + (size_t)n * 64 + l * 8);
    float xv[4];
    unpack4(sr.x, sr.y, xv);
    float o[4];
#pragma unroll
    for (int f = 0; f < 4; f++) o[f] = s_b[4 * l + f];
#pragma unroll
    for (int i2 = 0; i2 < 8; i2++) {
        float bm[4], bx[4];
#pragma unroll
        for (int r = 0; r < 4; r++) {
            bm[r] = __shfl(mx[r], i2, 8);
            bx[r] = __shfl(xv[r], i2, 8);
        }
#pragma unroll
        for (int r = 0; r < 4; r++) {
            const float4 wlv = *(const float4*)(s_wl + (4 * i2 + r) * DD + 4 * l);
            const float4 wrv = *(const float4*)(s_wr + (4 * i2 + r) * DD + 4 * l);
            o[0] += bm[r] * wlv.x + bx[r] * wrv.x;
            o[1] += bm[r] * wlv.y + bx[r] * wrv.y;
            o[2] += bm[r] * wlv.z + bx[r] * wrv.z;
            o[3] += bm[r] * wlv.w + bx[r] * wrv.w;
        }
    }
#pragma unroll
    for (int f = 0; f < 4; f++) o[f] = fmaxf(o[f], 0.f);
    uint2 ow;
    *reinterpret_cast<__half2*>(&ow.x) = __floats2half2_rn(o[0], o[1]);
    *reinterpret_cast<__half2*>(&ow.y) = __floats2half2_rn(o[2], o[3]);
    *(uint2*)((char*)out + (size_t)n * 64 + l * 8) = ow;
    if (a_s) {
        float pa0 = 0.f, pa1 = 0.f, pd0 = 0.f, pd1 = 0.f;
#pragma unroll
        for (int r = 0; r < 4; r++) {
            float4 c = s_c[4 * l + r];
            pa0 += o[r] * c.x;
            pa1 += o[r] * c.y;
            pd0 += o[r] * c.z;
            pd1 += o[r] * c.w;
        }
#pragma unroll
        for (int off = 4; off > 0; off >>= 1) {
            pa0 += __shfl_xor(pa0, off, 8);
            pa1 += __shfl_xor(pa1, off, 8);
            pd0 += __shfl_xor(pd0, off, 8);
            pd1 += __shfl_xor(pd1, off, 8);
        }
        if (l == 0) {
            a_s[n] = make_float2(pa0, pa1);
            a_d[n] = make_float2(pd0, pd1);
        }
    }
}

// ---- GAT aggregate v10: 8 lanes/node, inline softmax weights, half4 gathers
// -> W transform -> head-mean+bias+relu -> fused mlp-pre ----
__global__ void gat_agg_v10(const __half* __restrict__ x2, const float2* __restrict__ a_s,
                            const float2* __restrict__ a_d, const int* __restrict__ rowptr,
                            const int* __restrict__ soff, const float* __restrict__ gw,
                            const float* __restrict__ bias, const float* __restrict__ w1,
                            const float* __restrict__ b1, __half* __restrict__ Ps,
                            __half* __restrict__ Pd, int N) {
    __shared__ float s_gw[DD * HH * DD];  // gat W: 32 x 64
    __shared__ float s_w1[2 * DD * DD];   // mlp w1 rows 0..63
    __shared__ float s_b1[DD];
    __shared__ float s_bias[DD];
    int t = threadIdx.x;
    for (int i = t; i < DD * HH * DD; i += blockDim.x) s_gw[i] = gw[i];
    for (int i = t; i < 2 * DD * DD; i += blockDim.x) s_w1[i] = w1[i];
    if (t < DD) {
        s_b1[t] = b1[t];
        s_bias[t] = bias[t];
    }
    __syncthreads();
    int gid = blockIdx.x * blockDim.x + t;
    int n = gid >> 3;
    if (n >= N) return;
    int l = gid & 7;
    const char* xb = (const char*)x2;
    const char* asb = (const char*)a_s;
    int lo = rowptr[n], hi = rowptr[n + 1];
    float2 as = a_s[n], ad = a_d[n];
    float ws0 = __expf(lrelu(as.x + ad.x));
    float ws1 = __expf(lrelu(as.y + ad.y));
    uint2 sr = *(const uint2*)(xb + (size_t)n * 64 + l * 8);
    float xvs[4];
    unpack4(sr.x, sr.y, xvs);
    float den0 = ws0, den1 = ws1;
    float y0[4], y1[4];
#pragma unroll
    for (int f = 0; f < 4; f++) {
        y0[f] = ws0 * xvs[f];
        y1[f] = ws1 * xvs[f];
    }
    int j = lo;
    for (; j + 3 < hi; j += 4) {
        int o0 = soff[j], o1 = soff[j + 1], o2 = soff[j + 2], o3 = soff[j + 3];
        float2 s0 = *(const float2*)(asb + (o0 >> 3));
        float2 s1 = *(const float2*)(asb + (o1 >> 3));
        float2 s2 = *(const float2*)(asb + (o2 >> 3));
        float2 s3 = *(const float2*)(asb + (o3 >> 3));
        uint2 r0 = *(const uint2*)(xb + o0 + l * 8);
        uint2 r1 = *(const uint2*)(xb + o1 + l * 8);
        uint2 r2 = *(const uint2*)(xb + o2 + l * 8);
        uint2 r3 = *(const uint2*)(xb + o3 + l * 8);
        float w00 = __expf(lrelu(s0.x + ad.x)), w01 = __expf(lrelu(s0.y + ad.y));
        float w10 = __expf(lrelu(s1.x + ad.x)), w11 = __expf(lrelu(s1.y + ad.y));
        float w20 = __expf(lrelu(s2.x + ad.x)), w21 = __expf(lrelu(s2.y + ad.y));
        float w30 = __expf(lrelu(s3.x + ad.x)), w31 = __expf(lrelu(s3.y + ad.y));
        den0 += (w00 + w10) + (w20 + w30);
        den1 += (w01 + w11) + (w21 + w31);
        float v0[4], v1[4], v2[4], v3[4];
        unpack4(r0.x, r0.y, v0);
        unpack4(r1.x, r1.y, v1);
        unpack4(r2.x, r2.y, v2);
        unpack4(r3.x, r3.y, v3);
#pragma unroll
        for (int f = 0; f < 4; f++) {
            y0[f] += (w00 * v0[f] + w10 * v1[f]) + (w20 * v2[f] + w30 * v3[f]);
            y1[f] += (w01 * v0[f] + w11 * v1[f]) + (w21 * v2[f] + w31 * v3[f]);
        }
    }
    for (; j < hi; j++) {
        int o0 = soff[j];
        float2 s0 = *(const float2*)(asb + (o0 >> 3));
        uint2 r0 = *(const uint2*)(xb + o0 + l * 8);
        float w00 = __expf(lrelu(s0.x + ad.x)), w01 = __expf(lrelu(s0.y + ad.y));
        den0 += w00;
        den1 += w01;
        float v0[4];
        unpack4(r0.x, r0.y, v0);
#pragma unroll
        for (int f = 0; f < 4; f++) {
            y0[f] += w00 * v0[f];
            y1[f] += w01 * v0[f];
        }
    }
    float i0 = 1.0f / (den0 + 1e-16f), i1 = 1.0f / (den1 + 1e-16f);
    float u0[4], u1[4];
#pragma unroll
    for (int f = 0; f < 4; f++) {
        u0[f] = y0[f] * i0;
        u1[f] = y1[f] * i1;
    }
    // o[kk] = 0.5*(sum_i u0[i] gw[i][kk] + u1[i] gw[i][32+kk]) + bias, relu
    float o[4] = {0.f, 0.f, 0.f, 0.f};
#pragma unroll
    for (int i2 = 0; i2 < 8; i2++) {
        float b0[4], b1v[4];
#pragma unroll
        for (int r = 0; r < 4; r++) {
            b0[r] = __shfl(u0[r], i2, 8);
            b1v[r] = __shfl(u1[r], i2, 8);
        }
#pragma unroll
        for (int r = 0; r < 4; r++) {
            const float4 g0 = *(const float4*)(s_gw + (4 * i2 + r) * (HH * DD) + 4 * l);
            const float4 g1 = *(const float4*)(s_gw + (4 * i2 + r) * (HH * DD) + DD + 4 * l);
            o[0] += b0[r] * g0.x + b1v[r] * g1.x;
            o[1] += b0[r] * g0.y + b1v[r] * g1.y;
            o[2] += b0[r] * g0.z + b1v[r] * g1.z;
            o[3] += b0[r] * g0.w + b1v[r] * g1.w;
        }
    }
#pragma unroll
    for (int f = 0; f < 4; f++) o[f] = fmaxf(0.5f * o[f] + s_bias[4 * l + f], 0.f);
    // fused mlp-pre: Ps (rows 0..31 of w1, +b1), Pd (rows 32..63)
    float ps[4], pd[4];
#pragma unroll
    for (int f = 0; f < 4; f++) {
        ps[f] = s_b1[4 * l + f];
        pd[f] = 0.f;
    }
#pragma unroll
    for (int i2 = 0; i2 < 8; i2++) {
        float bo[4];
#pragma unroll
        for (int r = 0; r < 4; r++) bo[r] = __shfl(o[r], i2, 8);
#pragma unroll
        for (int r = 0; r < 4; r++) {
            const float4 wa = *(const float4*)(s_w1 + (4 * i2 + r) * DD + 4 * l);
            const float4 wb = *(const float4*)(s_w1 + (DD + 4 * i2 + r) * DD + 4 * l);
            ps[0] += bo[r] * wa.x;
            ps[1] += bo[r] * wa.y;
            ps[2] += bo[r] * wa.z;
            ps[3] += bo[r] * wa.w;
            pd[0] += bo[r] * wb.x;
            pd[1] += bo[r] * wb.y;
            pd[2] += bo[r] * wb.z;
            pd[3] += bo[r] * wb.w;
        }
    }
    uint2 pw;
    *reinterpret_cast<__half2*>(&pw.x) = __floats2half2_rn(ps[0], ps[1]);
    *reinterpret_cast<__half2*>(&pw.y) = __floats2half2_rn(ps[2], ps[3]);
    *(uint2*)((char*)Ps + (size_t)n * 64 + l * 8) = pw;
    *reinterpret_cast<__half2*>(&pw.x) = __floats2half2_rn(pd[0], pd[1]);
    *reinterpret_cast<__half2*>(&pw.y) = __floats2half2_rn(pd[2], pd[3]);
    *(uint2*)((char*)Pd + (size_t)n * 64 + l * 8) = pw;
}

// ---- Edge MLP: acc = Ps[s] + Pd[d] + W1e*ea; out = relu(acc) . w2 + b2 ----
// one thread per edge, straight-line body
__device__ __forceinline__ void add_half_row(const __half* __restrict__ row, float acc[DD]) {
    const uint4* r4 = (const uint4*)row;
#pragma unroll
    for (int c = 0; c < 4; c++) {
        uint4 u = r4[c];
        unsigned uu[4] = {u.x, u.y, u.z, u.w};
#pragma unroll
        for (int t = 0; t < 4; t++) {
            __half2 h2 = *reinterpret_cast<const __half2*>(&uu[t]);
            float2 f = __half22float2(h2);
            acc[c * 8 + t * 2 + 0] += f.x;
            acc[c * 8 + t * 2 + 1] += f.y;
        }
    }
}

__global__ void edge_mlp_v3(const __half* __restrict__ Ps, const __half* __restrict__ Pd,
                            const float* __restrict__ eattr, const int* __restrict__ src,
                            const int* __restrict__ dst, const float* __restrict__ w1e,
                            const float* __restrict__ w2, const float* __restrict__ b2,
                            float* __restrict__ out, int E) {
    __shared__ float s_we[EFF * DD];  // rows 64..79 of w1
    __shared__ float s_w2[DD];
    for (int i = threadIdx.x; i < EFF * DD; i += blockDim.x) s_we[i] = w1e[i];
    if (threadIdx.x < DD) s_w2[threadIdx.x] = w2[threadIdx.x];
    __syncthreads();
    int e = blockIdx.x * blockDim.x + threadIdx.x;
    if (e >= E) return;
    float b2v = b2[0];
    int s = src[e], d = dst[e];
    float acc[DD] = {};
    add_half_row(Ps + (size_t)s * DD, acc);
    add_half_row(Pd + (size_t)d * DD, acc);
    const float4* ea4 = (const float4*)(eattr + (size_t)e * EFF);
#pragma unroll
    for (int c = 0; c < 4; c++) {
        float4 v = ea4[c];
        const float va[4] = {v.x, v.y, v.z, v.w};
#pragma unroll
        for (int r = 0; r < 4; r++) {
#pragma unroll
            for (int j4 = 0; j4 < 8; j4++) {
                const float4 w = *(const float4*)(s_we + (c * 4 + r) * DD + j4 * 4);
                acc[j4 * 4 + 0] += va[r] * w.x;
                acc[j4 * 4 + 1] += va[r] * w.y;
                acc[j4 * 4 + 2] += va[r] * w.z;
                acc[j4 * 4 + 3] += va[r] * w.w;
            }
        }
    }
    float p = b2v;
#pragma unroll
    for (int j = 0; j < DD; j++) p += fmaxf(acc[j], 0.f) * s_w2[j];
    out[e] = p;
}

extern "C" void kernel_launch(void* const* d_in, const int* in_sizes, int n_in,
                              void* d_out, int out_size, void* d_ws, size_t ws_size,
                              hipStream_t stream) {
    const int E = in_sizes[0] / 2;
    const int N = in_sizes[2] / DD;

    const int* src = (const int*)d_in[0];
    const int* dst = src + E;
    const float* edge_attr = (const float*)d_in[1];
    const float* node_emb = (const float*)d_in[2];
    const float* sage1_wl = (const float*)d_in[3];
    const float* sage1_bl = (const float*)d_in[4];
    const float* sage1_wr = (const float*)d_in[5];
    const float* sage2_wl = (const float*)d_in[6];
    const float* sage2_bl = (const float*)d_in[7];
    const float* sage2_wr = (const float*)d_in[8];
    const float* gat_w = (const float*)d_in[9];
    const float* gat_att_src = (const float*)d_in[10];
    const float* gat_att_dst = (const float*)d_in[11];
    const float* gat_bias = (const float*)d_in[12];
    const float* mlp_w1 = (const float*)d_in[13];
    const float* mlp_b1 = (const float*)d_in[14];
    const float* mlp_w2 = (const float*)d_in[15];
    const float* mlp_b2 = (const float*)d_in[16];
    float* out = (float*)d_out;

    const int NBINS = (N + 255) >> BIN_SHIFT;
    const int NBLK = (E + EB - 1) / EB;
    const int M = NBINS * NBLK;

    // Workspace layout (256B-aligned chunks)
    char* ws = (char*)d_ws;
    size_t off = 0;
    auto alloc = [&](size_t bytes) {
        char* p = ws + off;
        off = (off + bytes + 255) & ~(size_t)255;
        return p;
    };
    int* rowptr = (int*)alloc((size_t)(N + 1) * 4);
    int* blockSums = (int*)alloc(256 * 4);
    int* dTot = (int*)alloc(4);
    int* soff = (int*)alloc((size_t)E * 4);
    __half* x0h = (__half*)alloc((size_t)N * DD * 2);
    __half* x1h = (__half*)alloc((size_t)N * DD * 2);
    __half* x2h = (__half*)alloc((size_t)N * DD * 2);
    float2* a_s = (float2*)alloc((size_t)N * 8);
    float2* a_d = (float2*)alloc((size_t)N * 8);
    float4* c4 = (float4*)alloc(DD * 16);
    __half* Ps = (__half*)alloc((size_t)N * DD * 2);
    __half* Pd = (__half*)alloc((size_t)N * DD * 2);
    int* histA = (int*)alloc((size_t)M * 4);
    int* histScan = (int*)alloc((size_t)M * 4);
    int* pairs = (int*)alloc((size_t)E * 4);

    const int BS = 256;
    const int gE = (E + BS - 1) / BS;
    const int gN32 = (N * 32 + BS - 1) / BS;
    const int gN8 = (N * 8 + BS - 1) / BS;
    const int NBm = (M + 1023) / 1024;

    // ---- CSR build: counting sort; rowptr built inside radixC ----
    radixA_k<<<NBLK, PB_T, 0, stream>>>(dst, histA, E, NBLK, NBINS);
    scan1_k<<<NBm, 256, 0, stream>>>(histA, histScan, blockSums, M);
    scan2_k<<<1, 256, 0, stream>>>(blockSums, dTot, NBm);
    scan3_k<<<(M + BS - 1) / BS, BS, 0, stream>>>(histScan, blockSums, M);
    radixB_k<<<NBLK, PB_T, 0, stream>>>(src, dst, histScan, pairs, E, NBLK, NBINS);
    radixC_v2<<<NBINS, 256, 0, stream>>>(histScan, pairs, rowptr, soff, N, NBLK, NBINS, E);

    // ---- fp16 input conversion + attention coefficient vectors ----
    cvt_k<<<gN32, BS, 0, stream>>>(node_emb, x0h, N * DD);
    prep_c_k<<<1, 64, 0, stream>>>(gat_w, gat_att_src, gat_att_dst, c4);

    // ---- SAGE layers (layer 2 also emits GAT scores) ----
    sage8x8_k<<<gN8, BS, 0, stream>>>(x0h, rowptr, soff, sage1_wl, sage1_bl, sage1_wr,
                                      x1h, nullptr, nullptr, nullptr, N);
    sage8x8_k<<<gN8, BS, 0, stream>>>(x1h, rowptr, soff, sage2_wl, sage2_bl, sage2_wr,
                                      x2h, c4, a_s, a_d, N);

    // ---- GAT aggregate (+ inline softmax weights + fused mlp-pre) ----
    gat_agg_v10<<<gN8, BS, 0, stream>>>(x2h, a_s, a_d, rowptr, soff, gat_w, gat_bias,
                                        mlp_w1, mlp_b1, Ps, Pd, N);

    // ---- Edge MLP ----
    edge_mlp_v3<<<gE, BS, 0, stream>>>(Ps, Pd, edge_attr, src, dst,
                                       mlp_w1 + 2 * DD * DD, mlp_w2, mlp_b2, out, E);
}